// Round 1
// baseline (364.306 us; speedup 1.0000x reference)
//
#include <hip/hip_runtime.h>
#include <cstddef>

#define N_ST 256
#define TWO_N 512
#define NU 128
#define BATCH 16
#define TSTEPS 2048
#define H_STEP 0.01f
#define EPS_V 0.001f
#define NCHUNK 16
#define CHUNKL (TSTEPS / NCHUNK)   // 128

// workspace layout (float offsets)
#define OFF_S      0                       // 16*2048*512 = 16777216 floats (forcing, then scan output Z, in place)
#define OFF_W      16777216                // 512*512  (Wt[c][j]: state-dim c -> output-dim j)
#define OFF_WF     (OFF_W + 262144)        // 128*512  (Wf[k][c] = h * Bc weights, transposed)
#define OFF_D      (OFF_WF + 65536)        // dr[256], di[256], dLre[256], dLim[256]
#define OFF_XBAR0  (OFF_D + 1024)          // 16*512
#define OFF_E      (OFF_XBAR0 + 8192)      // 16*16*512 chunk forced-end states
#define OFF_CINIT  (OFF_E + 131072)        // 16*16*512 chunk initial states

// ---- precompute kernels ----

__global__ void prep_W(const float* __restrict__ P_re, const float* __restrict__ P_im,
                       float* __restrict__ Wt) {
    int idx = blockIdx.x * blockDim.x + threadIdx.x;   // 262144
    int j = idx >> 9;          // output dim 0..511
    int c = idx & 511;         // state dim 0..511
    float v;
    if (c < N_ST) v = P_re[j * TWO_N + c] + P_re[j * TWO_N + c + N_ST];
    else          v = P_im[j * TWO_N + c] - P_im[j * TWO_N + c - N_ST];
    Wt[c * TWO_N + j] = v;     // transposed for GEMM: Bw[k=c][n=j]
}

__global__ void prep_Wf(const float* __restrict__ B_re, const float* __restrict__ B_im,
                        float* __restrict__ Wf) {
    int idx = blockIdx.x * blockDim.x + threadIdx.x;   // 65536
    int k = idx >> 9;          // input dim 0..127
    int c = idx & 511;         // state dim 0..511
    float v = (c < N_ST) ? B_re[c * NU + k] : B_im[(c - N_ST) * NU + k];
    Wf[k * TWO_N + c] = H_STEP * v;
}

__global__ void prep_d(const float* __restrict__ alpha, const float* __restrict__ theta,
                       float* __restrict__ dbuf) {
    int i = threadIdx.x;       // 256
    float dr = 1.0f + H_STEP * (-expf(alpha[i]) - EPS_V);
    float di = H_STEP * theta[i];
    float pr = 1.0f, pi = 0.0f;
    for (int k = 0; k < CHUNKL; ++k) { float nr = pr * dr - pi * di; pi = pr * di + pi * dr; pr = nr; }
    dbuf[i] = dr; dbuf[N_ST + i] = di; dbuf[2 * N_ST + i] = pr; dbuf[3 * N_ST + i] = pi;
}

__global__ void xbar0_kernel(const float* __restrict__ Pinv_re, const float* __restrict__ Pinv_im,
                             const float* __restrict__ xi0, float* __restrict__ xbar0) {
    int b = blockIdx.x; int i = threadIdx.x;   // 16 x 256
    __shared__ float xs[TWO_N];
    for (int j = threadIdx.x; j < TWO_N; j += blockDim.x) xs[j] = xi0[b * TWO_N + j];
    __syncthreads();
    float re = 0.f, im = 0.f;
    for (int j = 0; j < TWO_N; ++j) {
        float x = xs[j];
        re += Pinv_re[i * TWO_N + j] * x;
        im += Pinv_im[i * TWO_N + j] * x;
    }
    xbar0[b * TWO_N + i] = re;
    xbar0[b * TWO_N + N_ST + i] = im;
}

// ---- f32 tiled GEMM: C[M][512] = A[M][K] @ Bw[K][512] ----
template <int K>
__global__ __launch_bounds__(256) void gemm_f32(const float* __restrict__ A,
                                                const float* __restrict__ Bw,
                                                float* __restrict__ C) {
    __shared__ float As[16][68];   // [k][m]
    __shared__ float Bs[16][68];   // [k][n]
    int tid = threadIdx.x;
    int tx = tid & 15, ty = tid >> 4;
    int m0 = blockIdx.x * 64, n0 = blockIdx.y * 64;
    float acc[4][4] = {};
    for (int kk = 0; kk < K; kk += 16) {
        {
            int l = tid * 4;
            int m = l >> 4, k0 = l & 15;
            float4 a = *reinterpret_cast<const float4*>(&A[(size_t)(m0 + m) * K + kk + k0]);
            As[k0 + 0][m] = a.x; As[k0 + 1][m] = a.y; As[k0 + 2][m] = a.z; As[k0 + 3][m] = a.w;
        }
        {
            int l = tid * 4;
            int k = l >> 6, n = l & 63;
            *reinterpret_cast<float4*>(&Bs[k][n]) =
                *reinterpret_cast<const float4*>(&Bw[(size_t)(kk + k) * TWO_N + n0 + n]);
        }
        __syncthreads();
#pragma unroll
        for (int k = 0; k < 16; ++k) {
            float4 av = *reinterpret_cast<const float4*>(&As[k][ty * 4]);
            float4 bv = *reinterpret_cast<const float4*>(&Bs[k][tx * 4]);
            float a[4] = {av.x, av.y, av.z, av.w};
            float b[4] = {bv.x, bv.y, bv.z, bv.w};
#pragma unroll
            for (int i = 0; i < 4; ++i)
#pragma unroll
                for (int j = 0; j < 4; ++j) acc[i][j] += a[i] * b[j];
        }
        __syncthreads();
    }
#pragma unroll
    for (int i = 0; i < 4; ++i) {
        float4 o = {acc[i][0], acc[i][1], acc[i][2], acc[i][3]};
        *reinterpret_cast<float4*>(&C[(size_t)(m0 + ty * 4 + i) * TWO_N + n0 + tx * 4]) = o;
    }
}

// ---- 3-pass chunked diagonal scan ----
__global__ void scan_passA(const float* __restrict__ S, const float* __restrict__ dbuf,
                           float* __restrict__ e) {
    int b = blockIdx.x, c = blockIdx.y, i = threadIdx.x;
    float dr = dbuf[i], di = dbuf[N_ST + i];
    const float* Sp = S + ((size_t)b * TSTEPS + (size_t)c * CHUNKL) * TWO_N;
    float re = 0.f, im = 0.f;
    for (int j = 0; j < CHUNKL; ++j) {
        float fr = Sp[(size_t)j * TWO_N + i];
        float fi = Sp[(size_t)j * TWO_N + N_ST + i];
        float nre = dr * re - di * im + fr;
        float nim = dr * im + di * re + fi;
        re = nre; im = nim;
    }
    e[((size_t)(b * NCHUNK + c)) * TWO_N + i] = re;
    e[((size_t)(b * NCHUNK + c)) * TWO_N + N_ST + i] = im;
}

__global__ void scan_passB(const float* __restrict__ e, const float* __restrict__ dbuf,
                           const float* __restrict__ xbar0, float* __restrict__ cinit) {
    int b = blockIdx.x, i = threadIdx.x;
    float dLr = dbuf[2 * N_ST + i], dLi = dbuf[3 * N_ST + i];
    float re = xbar0[b * TWO_N + i], im = xbar0[b * TWO_N + N_ST + i];
    for (int c = 0; c < NCHUNK; ++c) {
        size_t o = ((size_t)(b * NCHUNK + c)) * TWO_N;
        cinit[o + i] = re;
        cinit[o + N_ST + i] = im;
        float er = e[o + i], ei = e[o + N_ST + i];
        float nre = dLr * re - dLi * im + er;
        float nim = dLr * im + dLi * re + ei;
        re = nre; im = nim;
    }
}

__global__ void scan_passC(float* __restrict__ S, const float* __restrict__ dbuf,
                           const float* __restrict__ cinit) {
    int b = blockIdx.x, c = blockIdx.y, i = threadIdx.x;
    float dr = dbuf[i], di = dbuf[N_ST + i];
    size_t o = ((size_t)(b * NCHUNK + c)) * TWO_N;
    float re = cinit[o + i], im = cinit[o + N_ST + i];
    float* Sp = S + ((size_t)b * TSTEPS + (size_t)c * CHUNKL) * TWO_N;
    for (int j = 0; j < CHUNKL; ++j) {
        float fr = Sp[(size_t)j * TWO_N + i];
        float fi = Sp[(size_t)j * TWO_N + N_ST + i];
        float nre = dr * re - di * im + fr;
        float nim = dr * im + di * re + fi;
        re = nre; im = nim;
        Sp[(size_t)j * TWO_N + i] = re;        // Z[b][t] = x_bar^{(t+1)}
        Sp[(size_t)j * TWO_N + N_ST + i] = im;
    }
}

__global__ void copy_t0(const float* __restrict__ xi0, float* __restrict__ out) {
    int b = blockIdx.x, j = threadIdx.x;   // 16 x 512
    out[(size_t)b * TSTEPS * TWO_N + j] = xi0[b * TWO_N + j];
}

extern "C" void kernel_launch(void* const* d_in, const int* in_sizes, int n_in,
                              void* d_out, int out_size, void* d_ws, size_t ws_size,
                              hipStream_t stream) {
    const float* xi_init = (const float*)d_in[0];
    const float* u_log   = (const float*)d_in[1];
    const float* alpha   = (const float*)d_in[2];
    const float* theta   = (const float*)d_in[3];
    const float* B_re    = (const float*)d_in[4];
    const float* B_im    = (const float*)d_in[5];
    const float* P_re    = (const float*)d_in[6];
    const float* P_im    = (const float*)d_in[7];
    const float* Pinv_re = (const float*)d_in[8];
    const float* Pinv_im = (const float*)d_in[9];
    float* out = (float*)d_out;
    float* ws  = (float*)d_ws;

    float* S     = ws + OFF_S;
    float* Wt    = ws + OFF_W;
    float* Wf    = ws + OFF_WF;
    float* dbuf  = ws + OFF_D;
    float* xbar0 = ws + OFF_XBAR0;
    float* e     = ws + OFF_E;
    float* cinit = ws + OFF_CINIT;

    prep_W<<<1024, 256, 0, stream>>>(P_re, P_im, Wt);
    prep_Wf<<<256, 256, 0, stream>>>(B_re, B_im, Wf);
    prep_d<<<1, 256, 0, stream>>>(alpha, theta, dbuf);
    xbar0_kernel<<<16, 256, 0, stream>>>(Pinv_re, Pinv_im, xi_init, xbar0);

    // forcing: S[b*T+t][c] = h * (Bc u_t)  (re | im)
    gemm_f32<NU><<<dim3((BATCH * TSTEPS) / 64, TWO_N / 64), 256, 0, stream>>>(u_log, Wf, S);

    // chunked diagonal scan (in place: S becomes Z, Z[b][t] = x_bar^{(t+1)})
    scan_passA<<<dim3(BATCH, NCHUNK), 256, 0, stream>>>(S, dbuf, e);
    scan_passB<<<BATCH, 256, 0, stream>>>(e, dbuf, xbar0, cinit);
    scan_passC<<<dim3(BATCH, NCHUNK), 256, 0, stream>>>(S, dbuf, cinit);

    // output projection: out[b][t][:] = W @ z  (t>=1 rows valid; t=0 overwritten below)
    gemm_f32<TWO_N><<<dim3((BATCH * TSTEPS) / 64, TWO_N / 64), 256, 0, stream>>>(S, Wt, out);

    copy_t0<<<BATCH, TWO_N, 0, stream>>>(xi_init, out);
}

// Round 2
// 147.708 us; speedup vs baseline: 2.4664x; 2.4664x over previous
//
#include <hip/hip_runtime.h>
#include <hip/hip_bf16.h>
#include <cstddef>
#include <cstdint>

#define N_ST 256
#define TWO_N 512
#define NU 128
#define BATCH 16
#define TSTEPS 2048
#define MTOT (BATCH * TSTEPS)   // 32768
#define H_STEP 0.01f
#define EPS_V 0.001f
#define NCHUNK 16
#define CHUNKL 128

typedef __attribute__((ext_vector_type(4))) float f32x4;
typedef __attribute__((ext_vector_type(4))) short s16x4;
typedef __attribute__((ext_vector_type(8))) short s16x8;

// ---- workspace layout (float offsets) ----
// S      : 16777216 f32   (67 MB)  forcing, f32, plain [m][512]
// Zpk    : 16777216 short (33 MB)  packed bf16 Z: [(m>>4)][k=512][m&15]
// upk    :  4194304 short ( 8 MB)  packed bf16 u: [(m>>4)][k=128][m&15]
// Wtpk   :   262144 short          packed bf16 Wt: [(n>>4)][k=512][n&15]
// Wfpk   :    65536 short          packed bf16 Wf: [(n>>4)][k=128][n&15]
#define OFF_S      0
#define OFF_ZPK    16777216
#define OFF_UPK    25165824
#define OFF_WT     27262976
#define OFF_WF     27394048
#define OFF_D      27426816
#define OFF_XBAR0  27427840
#define OFF_E      27436032
#define OFF_CINIT  27567104

// ---- precompute kernels ----

__global__ void prep_W(const float* __restrict__ P_re, const float* __restrict__ P_im,
                       __hip_bfloat16* __restrict__ Wtpk) {
    int idx = blockIdx.x * blockDim.x + threadIdx.x;   // 262144
    int j = idx >> 9;          // output dim (n) 0..511
    int c = idx & 511;         // state dim (k) 0..511
    float v;
    if (c < N_ST) v = P_re[j * TWO_N + c] + P_re[j * TWO_N + c + N_ST];
    else          v = P_im[j * TWO_N + c] - P_im[j * TWO_N + c - N_ST];
    Wtpk[((size_t)(j >> 4) * TWO_N + c) * 16 + (j & 15)] = __float2bfloat16(v);
}

__global__ void prep_Wf(const float* __restrict__ B_re, const float* __restrict__ B_im,
                        __hip_bfloat16* __restrict__ Wfpk) {
    int idx = blockIdx.x * blockDim.x + threadIdx.x;   // 65536
    int k = idx >> 9;          // input dim (k) 0..127
    int c = idx & 511;         // state dim (n) 0..511
    float v = (c < N_ST) ? B_re[c * NU + k] : B_im[(c - N_ST) * NU + k];
    Wfpk[((size_t)(c >> 4) * NU + k) * 16 + (c & 15)] = __float2bfloat16(H_STEP * v);
}

__global__ void upack(const float* __restrict__ u, __hip_bfloat16* __restrict__ upk) {
    int idx = blockIdx.x * blockDim.x + threadIdx.x;   // 4194304
    int m = idx >> 7, k = idx & 127;
    upk[((size_t)(m >> 4) * NU + k) * 16 + (m & 15)] = __float2bfloat16(u[idx]);
}

__global__ void prep_d(const float* __restrict__ alpha, const float* __restrict__ theta,
                       float* __restrict__ dbuf) {
    int i = threadIdx.x;       // 256
    float dr = 1.0f + H_STEP * (-expf(alpha[i]) - EPS_V);
    float di = H_STEP * theta[i];
    float pr = 1.0f, pi = 0.0f;
    for (int k = 0; k < CHUNKL; ++k) { float nr = pr * dr - pi * di; pi = pr * di + pi * dr; pr = nr; }
    dbuf[i] = dr; dbuf[N_ST + i] = di; dbuf[2 * N_ST + i] = pr; dbuf[3 * N_ST + i] = pi;
}

__global__ void xbar0_kernel(const float* __restrict__ Pinv_re, const float* __restrict__ Pinv_im,
                             const float* __restrict__ xi0, float* __restrict__ xbar0) {
    int b = blockIdx.x; int i = threadIdx.x;   // 16 x 256
    __shared__ float xs[TWO_N];
    for (int j = threadIdx.x; j < TWO_N; j += blockDim.x) xs[j] = xi0[b * TWO_N + j];
    __syncthreads();
    float re = 0.f, im = 0.f;
    for (int j = 0; j < TWO_N; ++j) {
        float x = xs[j];
        re += Pinv_re[i * TWO_N + j] * x;
        im += Pinv_im[i * TWO_N + j] * x;
    }
    xbar0[b * TWO_N + i] = re;
    xbar0[b * TWO_N + N_ST + i] = im;
}

// ---- bf16 MFMA GEMM: C[M][512](f32) = Apk[M][K](bf16,packed) @ Bpk[K][512](bf16,packed)
// Packed layout: elem(row,k) at [(row>>4)*K + k]*16 + (row&15).
// Tile 128x128, 4 waves (2x2), BK=32. Fragments via ds_read_b64_tr_b16.
template <int K>
__global__ __launch_bounds__(256) void gemm_mfma(const short* __restrict__ Apk,
                                                 const short* __restrict__ Bpk,
                                                 float* __restrict__ C) {
    __shared__ __align__(1024) short ldsA[4096];   // 8 slabs x [32 k][16 m]
    __shared__ __align__(1024) short ldsB[4096];   // 8 slabs x [32 k][16 n]
    const int tid = threadIdx.x;
    const int wid = tid >> 6, lane = tid & 63;
    const int m0 = blockIdx.x * 128, n0 = blockIdx.y * 128;
    const int wm = wid >> 1, wn = wid & 1;

    f32x4 acc[4][4] = {};

    const size_t slabStride = (size_t)K * 16;
    const unsigned aBase = (unsigned)(uintptr_t)(__attribute__((address_space(3))) short*)&ldsA[0];
    const unsigned bBase = (unsigned)(uintptr_t)(__attribute__((address_space(3))) short*)&ldsB[0];

    for (int kk = 0; kk < K; kk += 32) {
        // ---- stage: each wave loads 2 A slabs + 2 B slabs (1 KB each, fully coalesced)
        {
            const short* gA0 = Apk + ((size_t)(m0 >> 4) + wid)     * slabStride + (size_t)kk * 16 + lane * 8;
            const short* gA1 = Apk + ((size_t)(m0 >> 4) + wid + 4) * slabStride + (size_t)kk * 16 + lane * 8;
            const short* gB0 = Bpk + ((size_t)(n0 >> 4) + wid)     * slabStride + (size_t)kk * 16 + lane * 8;
            const short* gB1 = Bpk + ((size_t)(n0 >> 4) + wid + 4) * slabStride + (size_t)kk * 16 + lane * 8;
            __builtin_amdgcn_global_load_lds((const __attribute__((address_space(1))) void*)gA0,
                (__attribute__((address_space(3))) void*)&ldsA[(size_t)wid * 512], 16, 0, 0);
            __builtin_amdgcn_global_load_lds((const __attribute__((address_space(1))) void*)gA1,
                (__attribute__((address_space(3))) void*)&ldsA[(size_t)(wid + 4) * 512], 16, 0, 0);
            __builtin_amdgcn_global_load_lds((const __attribute__((address_space(1))) void*)gB0,
                (__attribute__((address_space(3))) void*)&ldsB[(size_t)wid * 512], 16, 0, 0);
            __builtin_amdgcn_global_load_lds((const __attribute__((address_space(1))) void*)gB1,
                (__attribute__((address_space(3))) void*)&ldsB[(size_t)(wid + 4) * 512], 16, 0, 0);
        }
        __syncthreads();   // drains vmcnt before any wave reads LDS

        // ---- fragments via hardware transpose-read
        s16x4 al[4], ah[4], bl[4], bh[4];
#pragma unroll
        for (int t = 0; t < 4; ++t) {
            unsigned ad = aBase + ((unsigned)(wm * 4 + t) << 10) + ((unsigned)lane << 3);
            unsigned bd = bBase + ((unsigned)(wn * 4 + t) << 10) + ((unsigned)lane << 3);
            asm volatile("ds_read_b64_tr_b16 %0, %1 offset:0"   : "=v"(al[t]) : "v"(ad));
            asm volatile("ds_read_b64_tr_b16 %0, %1 offset:512" : "=v"(ah[t]) : "v"(ad));
            asm volatile("ds_read_b64_tr_b16 %0, %1 offset:0"   : "=v"(bl[t]) : "v"(bd));
            asm volatile("ds_read_b64_tr_b16 %0, %1 offset:512" : "=v"(bh[t]) : "v"(bd));
        }
        asm volatile("s_waitcnt lgkmcnt(0)" ::: "memory");
        __builtin_amdgcn_sched_barrier(0);   // rule 18: keep MFMA after the wait

#pragma unroll
        for (int i = 0; i < 4; ++i) {
            s16x8 av = __builtin_shufflevector(al[i], ah[i], 0, 1, 2, 3, 4, 5, 6, 7);
#pragma unroll
            for (int j = 0; j < 4; ++j) {
                s16x8 bv = __builtin_shufflevector(bl[j], bh[j], 0, 1, 2, 3, 4, 5, 6, 7);
                acc[i][j] = __builtin_amdgcn_mfma_f32_16x16x32_bf16(av, bv, acc[i][j], 0, 0, 0);
            }
        }
        __syncthreads();   // protect LDS before next stage
    }

    // ---- epilogue: C/D layout col = lane&15, row = (lane>>4)*4 + reg  [m89]
    const int cn = lane & 15;
    const int rr = (lane >> 4) * 4;
#pragma unroll
    for (int i = 0; i < 4; ++i) {
        int mrow = m0 + (wm * 4 + i) * 16 + rr;
#pragma unroll
        for (int j = 0; j < 4; ++j) {
            int ncol = n0 + (wn * 4 + j) * 16 + cn;
            float* cp = C + (size_t)mrow * TWO_N + ncol;
#pragma unroll
            for (int r = 0; r < 4; ++r) cp[(size_t)r * TWO_N] = acc[i][j][r];
        }
    }
}

// ---- 3-pass chunked diagonal scan ----
__global__ void scan_passA(const float* __restrict__ S, const float* __restrict__ dbuf,
                           float* __restrict__ e) {
    int b = blockIdx.x, c = blockIdx.y, i = threadIdx.x;
    float dr = dbuf[i], di = dbuf[N_ST + i];
    const float* Sp = S + ((size_t)b * TSTEPS + (size_t)c * CHUNKL) * TWO_N;
    float re = 0.f, im = 0.f;
    for (int j = 0; j < CHUNKL; ++j) {
        float fr = Sp[(size_t)j * TWO_N + i];
        float fi = Sp[(size_t)j * TWO_N + N_ST + i];
        float nre = dr * re - di * im + fr;
        float nim = dr * im + di * re + fi;
        re = nre; im = nim;
    }
    e[((size_t)(b * NCHUNK + c)) * TWO_N + i] = re;
    e[((size_t)(b * NCHUNK + c)) * TWO_N + N_ST + i] = im;
}

__global__ void scan_passB(const float* __restrict__ e, const float* __restrict__ dbuf,
                           const float* __restrict__ xbar0, float* __restrict__ cinit) {
    int b = blockIdx.x, i = threadIdx.x;
    float dLr = dbuf[2 * N_ST + i], dLi = dbuf[3 * N_ST + i];
    float re = xbar0[b * TWO_N + i], im = xbar0[b * TWO_N + N_ST + i];
    for (int c = 0; c < NCHUNK; ++c) {
        size_t o = ((size_t)(b * NCHUNK + c)) * TWO_N;
        cinit[o + i] = re;
        cinit[o + N_ST + i] = im;
        float er = e[o + i], ei = e[o + N_ST + i];
        float nre = dLr * re - dLi * im + er;
        float nim = dLr * im + dLi * re + ei;
        re = nre; im = nim;
    }
}

__global__ void scan_passC(const float* __restrict__ S, const float* __restrict__ dbuf,
                           const float* __restrict__ cinit, __hip_bfloat16* __restrict__ Zpk) {
    int b = blockIdx.x, c = blockIdx.y, i = threadIdx.x;
    float dr = dbuf[i], di = dbuf[N_ST + i];
    size_t o = ((size_t)(b * NCHUNK + c)) * TWO_N;
    float re = cinit[o + i], im = cinit[o + N_ST + i];
    const float* Sp = S + ((size_t)b * TSTEPS + (size_t)c * CHUNKL) * TWO_N;
    int m = b * TSTEPS + c * CHUNKL;
    for (int j = 0; j < CHUNKL; ++j, ++m) {
        float fr = Sp[(size_t)j * TWO_N + i];
        float fi = Sp[(size_t)j * TWO_N + N_ST + i];
        float nre = dr * re - di * im + fr;
        float nim = dr * im + di * re + fi;
        re = nre; im = nim;
        size_t slab = (size_t)(m >> 4) * ((size_t)TWO_N * 16);
        Zpk[slab + (size_t)i * 16 + (m & 15)]          = __float2bfloat16(re);
        Zpk[slab + (size_t)(i + N_ST) * 16 + (m & 15)] = __float2bfloat16(im);
    }
}

__global__ void copy_t0(const float* __restrict__ xi0, float* __restrict__ out) {
    int b = blockIdx.x, j = threadIdx.x;   // 16 x 512
    out[(size_t)b * TSTEPS * TWO_N + j] = xi0[b * TWO_N + j];
}

extern "C" void kernel_launch(void* const* d_in, const int* in_sizes, int n_in,
                              void* d_out, int out_size, void* d_ws, size_t ws_size,
                              hipStream_t stream) {
    const float* xi_init = (const float*)d_in[0];
    const float* u_log   = (const float*)d_in[1];
    const float* alpha   = (const float*)d_in[2];
    const float* theta   = (const float*)d_in[3];
    const float* B_re    = (const float*)d_in[4];
    const float* B_im    = (const float*)d_in[5];
    const float* P_re    = (const float*)d_in[6];
    const float* P_im    = (const float*)d_in[7];
    const float* Pinv_re = (const float*)d_in[8];
    const float* Pinv_im = (const float*)d_in[9];
    float* out = (float*)d_out;
    float* ws  = (float*)d_ws;

    float* S    = ws + OFF_S;
    __hip_bfloat16* Zpk  = (__hip_bfloat16*)(ws + OFF_ZPK);
    __hip_bfloat16* upk  = (__hip_bfloat16*)(ws + OFF_UPK);
    __hip_bfloat16* Wtpk = (__hip_bfloat16*)(ws + OFF_WT);
    __hip_bfloat16* Wfpk = (__hip_bfloat16*)(ws + OFF_WF);
    float* dbuf  = ws + OFF_D;
    float* xbar0 = ws + OFF_XBAR0;
    float* e     = ws + OFF_E;
    float* cinit = ws + OFF_CINIT;

    prep_W<<<1024, 256, 0, stream>>>(P_re, P_im, Wtpk);
    prep_Wf<<<256, 256, 0, stream>>>(B_re, B_im, Wfpk);
    prep_d<<<1, 256, 0, stream>>>(alpha, theta, dbuf);
    xbar0_kernel<<<16, 256, 0, stream>>>(Pinv_re, Pinv_im, xi_init, xbar0);
    upack<<<(MTOT * NU) / 256, 256, 0, stream>>>(u_log, upk);

    // forcing: S = h * u @ Bc^T   (bf16 MFMA, f32 out)
    gemm_mfma<NU><<<dim3(MTOT / 128, 4), 256, 0, stream>>>((const short*)upk, (const short*)Wfpk, S);

    // chunked diagonal scan; passC emits packed bf16 Z
    scan_passA<<<dim3(BATCH, NCHUNK), 256, 0, stream>>>(S, dbuf, e);
    scan_passB<<<BATCH, 256, 0, stream>>>(e, dbuf, xbar0, cinit);
    scan_passC<<<dim3(BATCH, NCHUNK), 256, 0, stream>>>(S, dbuf, cinit, Zpk);

    // output projection: out = Z @ W^T   (bf16 MFMA, f32 out)
    gemm_mfma<TWO_N><<<dim3(MTOT / 128, 4), 256, 0, stream>>>((const short*)Zpk, (const short*)Wtpk, out);

    copy_t0<<<BATCH, TWO_N, 0, stream>>>(xi_init, out);
}

// Round 3
// 132.490 us; speedup vs baseline: 2.7497x; 1.1149x over previous
//
#include <hip/hip_runtime.h>
#include <hip/hip_bf16.h>
#include <cstddef>
#include <cstdint>

#define N_ST 256
#define TWO_N 512
#define NU 128
#define BATCH 16
#define TSTEPS 2048
#define MTOT (BATCH * TSTEPS)   // 32768
#define H_STEP 0.01f
#define EPS_V 0.001f
#define NCHUNK 32
#define CHUNKL 64

typedef __attribute__((ext_vector_type(4))) float f32x4;
typedef __attribute__((ext_vector_type(4))) short s16x4;
typedef __attribute__((ext_vector_type(8))) short s16x8;

// ---- workspace layout (float offsets) ----
// Fpk  : packed bf16 forcing [(m>>4)][k=512][m&15]  (16777216 shorts)
// Zpk  : packed bf16 Z, same layout
// upk  : packed bf16 u [(m>>4)][k=128][m&15]
// Wtpk : packed bf16 Wt [(n>>4)][k=512][n&15]
// Wfpk : packed bf16 Wf [(c>>4)][k=128][c&15]
#define OFF_FPK    0
#define OFF_ZPK    8388608
#define OFF_UPK    16777216
#define OFF_WT     18874368
#define OFF_WF     19005440
#define OFF_D      19038208
#define OFF_XBAR0  19039232
#define OFF_E      19047424
#define OFF_CINIT  19309568

// ---- precompute kernels ----

__global__ void prep_W(const float* __restrict__ P_re, const float* __restrict__ P_im,
                       __hip_bfloat16* __restrict__ Wtpk) {
    int idx = blockIdx.x * blockDim.x + threadIdx.x;   // 262144
    int j = idx >> 9;          // output dim (n) 0..511
    int c = idx & 511;         // state dim (k) 0..511
    float v;
    if (c < N_ST) v = P_re[j * TWO_N + c] + P_re[j * TWO_N + c + N_ST];
    else          v = P_im[j * TWO_N + c] - P_im[j * TWO_N + c - N_ST];
    Wtpk[((size_t)(j >> 4) * TWO_N + c) * 16 + (j & 15)] = __float2bfloat16(v);
}

__global__ void prep_Wf(const float* __restrict__ B_re, const float* __restrict__ B_im,
                        __hip_bfloat16* __restrict__ Wfpk) {
    int idx = blockIdx.x * blockDim.x + threadIdx.x;   // 65536
    int k = idx >> 9;          // input dim (k) 0..127
    int c = idx & 511;         // state dim (n) 0..511
    float v = (c < N_ST) ? B_re[c * NU + k] : B_im[(c - N_ST) * NU + k];
    Wfpk[((size_t)(c >> 4) * NU + k) * 16 + (c & 15)] = __float2bfloat16(H_STEP * v);
}

__global__ void upack(const float* __restrict__ u, __hip_bfloat16* __restrict__ upk) {
    int idx = blockIdx.x * blockDim.x + threadIdx.x;   // 4194304
    int m = idx >> 7, k = idx & 127;
    upk[((size_t)(m >> 4) * NU + k) * 16 + (m & 15)] = __float2bfloat16(u[idx]);
}

__global__ void prep_d(const float* __restrict__ alpha, const float* __restrict__ theta,
                       float* __restrict__ dbuf) {
    int i = threadIdx.x;       // 256
    float dr = 1.0f + H_STEP * (-expf(alpha[i]) - EPS_V);
    float di = H_STEP * theta[i];
    float pr = 1.0f, pi = 0.0f;
    for (int k = 0; k < CHUNKL; ++k) { float nr = pr * dr - pi * di; pi = pr * di + pi * dr; pr = nr; }
    dbuf[i] = dr; dbuf[N_ST + i] = di; dbuf[2 * N_ST + i] = pr; dbuf[3 * N_ST + i] = pi;
}

__global__ void xbar0_kernel(const float* __restrict__ Pinv_re, const float* __restrict__ Pinv_im,
                             const float* __restrict__ xi0, float* __restrict__ xbar0) {
    int b = blockIdx.x; int i = threadIdx.x;   // 16 x 256
    __shared__ float xs[TWO_N];
    for (int j = threadIdx.x; j < TWO_N; j += blockDim.x) xs[j] = xi0[b * TWO_N + j];
    __syncthreads();
    float re = 0.f, im = 0.f;
    for (int j = 0; j < TWO_N; ++j) {
        float x = xs[j];
        re += Pinv_re[i * TWO_N + j] * x;
        im += Pinv_im[i * TWO_N + j] * x;
    }
    xbar0[b * TWO_N + i] = re;
    xbar0[b * TWO_N + N_ST + i] = im;
}

// ---- bf16 MFMA GEMM, 2-phase pipelined (T3-minimum), 128x128 tile, 4 waves.
// Apk/Bpk packed: elem(row,k) at [(row>>4)*K + k]*16 + (row&15).
// PACKOUT=false: write f32 C[M][512]. PACKOUT=true: write packed bf16 (forcing).
template <int K, bool PACKOUT>
__global__ __launch_bounds__(256) void gemm_mfma(const short* __restrict__ Apk,
                                                 const short* __restrict__ Bpk,
                                                 float* __restrict__ Cf,
                                                 short* __restrict__ Cp) {
    __shared__ __align__(1024) short lds[16384];   // A: [buf]*4096, B: 8192+[buf]*4096
    const int tid = threadIdx.x;
    const int wid = tid >> 6, lane = tid & 63;
    const int m0 = blockIdx.x * 128, n0 = blockIdx.y * 128;
    const int wm = wid >> 1, wn = wid & 1;
    f32x4 acc[4][4] = {};
    const size_t slabStride = (size_t)K * 16;
    const unsigned ldsBase = (unsigned)(uintptr_t)(__attribute__((address_space(3))) short*)&lds[0];

#define STAGE(buf, kk)                                                                              \
    do {                                                                                            \
        const short* gA0 = Apk + ((size_t)(m0 >> 4) + wid)     * slabStride + (size_t)(kk) * 16 + lane * 8; \
        const short* gA1 = Apk + ((size_t)(m0 >> 4) + wid + 4) * slabStride + (size_t)(kk) * 16 + lane * 8; \
        const short* gB0 = Bpk + ((size_t)(n0 >> 4) + wid)     * slabStride + (size_t)(kk) * 16 + lane * 8; \
        const short* gB1 = Bpk + ((size_t)(n0 >> 4) + wid + 4) * slabStride + (size_t)(kk) * 16 + lane * 8; \
        __builtin_amdgcn_global_load_lds((const __attribute__((address_space(1))) void*)gA0,        \
            (__attribute__((address_space(3))) void*)&lds[(buf) * 4096 + wid * 512], 16, 0, 0);     \
        __builtin_amdgcn_global_load_lds((const __attribute__((address_space(1))) void*)gA1,        \
            (__attribute__((address_space(3))) void*)&lds[(buf) * 4096 + (wid + 4) * 512], 16, 0, 0); \
        __builtin_amdgcn_global_load_lds((const __attribute__((address_space(1))) void*)gB0,        \
            (__attribute__((address_space(3))) void*)&lds[8192 + (buf) * 4096 + wid * 512], 16, 0, 0); \
        __builtin_amdgcn_global_load_lds((const __attribute__((address_space(1))) void*)gB1,        \
            (__attribute__((address_space(3))) void*)&lds[8192 + (buf) * 4096 + (wid + 4) * 512], 16, 0, 0); \
    } while (0)

    STAGE(0, 0);
    asm volatile("s_waitcnt vmcnt(0)" ::: "memory");
    __syncthreads();
    int cur = 0;
    for (int kk = 0; kk < K; kk += 32) {
        if (kk + 32 < K) STAGE(cur ^ 1, kk + 32);   // prefetch next tile under current compute

        s16x4 al[4], ah[4], bl[4], bh[4];
        const unsigned aB = ldsBase + (unsigned)cur * 8192;
        const unsigned bB = ldsBase + 16384u + (unsigned)cur * 8192;
#pragma unroll
        for (int t = 0; t < 4; ++t) {
            unsigned ad = aB + ((unsigned)(wm * 4 + t) << 10) + ((unsigned)lane << 3);
            unsigned bd = bB + ((unsigned)(wn * 4 + t) << 10) + ((unsigned)lane << 3);
            asm volatile("ds_read_b64_tr_b16 %0, %1 offset:0"   : "=v"(al[t]) : "v"(ad));
            asm volatile("ds_read_b64_tr_b16 %0, %1 offset:512" : "=v"(ah[t]) : "v"(ad));
            asm volatile("ds_read_b64_tr_b16 %0, %1 offset:0"   : "=v"(bl[t]) : "v"(bd));
            asm volatile("ds_read_b64_tr_b16 %0, %1 offset:512" : "=v"(bh[t]) : "v"(bd));
        }
        asm volatile("s_waitcnt lgkmcnt(0)" ::: "memory");
        __builtin_amdgcn_sched_barrier(0);   // rule 18

#pragma unroll
        for (int i = 0; i < 4; ++i) {
            s16x8 av = __builtin_shufflevector(al[i], ah[i], 0, 1, 2, 3, 4, 5, 6, 7);
#pragma unroll
            for (int j = 0; j < 4; ++j) {
                s16x8 bv = __builtin_shufflevector(bl[j], bh[j], 0, 1, 2, 3, 4, 5, 6, 7);
                acc[i][j] = __builtin_amdgcn_mfma_f32_16x16x32_bf16(av, bv, acc[i][j], 0, 0, 0);
            }
        }
        asm volatile("s_waitcnt vmcnt(0)" ::: "memory");   // next tile's loads landed
        __syncthreads();
        cur ^= 1;
    }
#undef STAGE

    const int cn = lane & 15;
    const int g4 = (lane >> 4) * 4;
    if (!PACKOUT) {
        // C/D layout: col = lane&15, row = (lane>>4)*4 + reg  [m89]
#pragma unroll
        for (int i = 0; i < 4; ++i) {
            int mrow = m0 + (wm * 4 + i) * 16 + g4;
#pragma unroll
            for (int j = 0; j < 4; ++j) {
                int ncol = n0 + (wn * 4 + j) * 16 + cn;
                float* cp = Cf + (size_t)mrow * TWO_N + ncol;
#pragma unroll
                for (int r = 0; r < 4; ++r) cp[(size_t)r * TWO_N] = acc[i][j][r];
            }
        }
    } else {
        // build packed-bf16 tile image in LDS: [8 s][128 cwt][16 ml], 32 KB
#pragma unroll
        for (int i = 0; i < 4; ++i) {
            int s = wm * 4 + i;
#pragma unroll
            for (int j = 0; j < 4; ++j) {
                int cwt = wn * 64 + j * 16 + cn;
                s16x4 pv;
#pragma unroll
                for (int r = 0; r < 4; ++r) {
                    __hip_bfloat16 bb = __float2bfloat16(acc[i][j][r]);
                    pv[r] = *reinterpret_cast<short*>(&bb);
                }
                *reinterpret_cast<__shared__ s16x4*>(&lds[((s * 128 + cwt) << 4) + g4]) = pv;
            }
        }
        __syncthreads();
        // coalesced store: per t-slab, 128 cols x 16 = 2048 shorts contiguous in global
        size_t baseG = (size_t)(m0 >> 4) * ((size_t)TWO_N * 16) + (size_t)n0 * 16;
#pragma unroll
        for (int q = 0; q < 8; ++q) {
            *reinterpret_cast<s16x8*>(Cp + baseG + (size_t)q * (TWO_N * 16) + tid * 8) =
                *reinterpret_cast<const __shared__ s16x8*>(&lds[q * 2048 + tid * 8]);
        }
    }
}

// ---- 3-pass chunked diagonal scan over packed bf16 forcing ----
__global__ void scan_passA(const __hip_bfloat16* __restrict__ Fpk, const float* __restrict__ dbuf,
                           float* __restrict__ e) {
    int b = blockIdx.x, c = blockIdx.y, i = threadIdx.x;
    float dr = dbuf[i], di = dbuf[N_ST + i];
    float re = 0.f, im = 0.f;
    int m = b * TSTEPS + c * CHUNKL;
    for (int j = 0; j < CHUNKL; ++j, ++m) {
        size_t slab = (size_t)(m >> 4) * 8192;
        float fr = __bfloat162float(Fpk[slab + (size_t)i * 16 + (m & 15)]);
        float fi = __bfloat162float(Fpk[slab + (size_t)(i + N_ST) * 16 + (m & 15)]);
        float nre = dr * re - di * im + fr;
        float nim = dr * im + di * re + fi;
        re = nre; im = nim;
    }
    size_t o = ((size_t)(b * NCHUNK + c)) * TWO_N;
    e[o + i] = re;
    e[o + N_ST + i] = im;
}

__global__ void scan_passB(const float* __restrict__ e, const float* __restrict__ dbuf,
                           const float* __restrict__ xbar0, float* __restrict__ cinit) {
    int b = blockIdx.x, i = threadIdx.x;
    float dLr = dbuf[2 * N_ST + i], dLi = dbuf[3 * N_ST + i];
    float re = xbar0[b * TWO_N + i], im = xbar0[b * TWO_N + N_ST + i];
    for (int c = 0; c < NCHUNK; ++c) {
        size_t o = ((size_t)(b * NCHUNK + c)) * TWO_N;
        cinit[o + i] = re;
        cinit[o + N_ST + i] = im;
        float er = e[o + i], ei = e[o + N_ST + i];
        float nre = dLr * re - dLi * im + er;
        float nim = dLr * im + dLi * re + ei;
        re = nre; im = nim;
    }
}

__global__ void scan_passC(const __hip_bfloat16* __restrict__ Fpk, const float* __restrict__ dbuf,
                           const float* __restrict__ cinit, __hip_bfloat16* __restrict__ Zpk) {
    int b = blockIdx.x, c = blockIdx.y, i = threadIdx.x;
    float dr = dbuf[i], di = dbuf[N_ST + i];
    size_t o = ((size_t)(b * NCHUNK + c)) * TWO_N;
    float re = cinit[o + i], im = cinit[o + N_ST + i];
    int m = b * TSTEPS + c * CHUNKL;
    for (int j = 0; j < CHUNKL; ++j, ++m) {
        size_t slab = (size_t)(m >> 4) * 8192;
        int ml = m & 15;
        float fr = __bfloat162float(Fpk[slab + (size_t)i * 16 + ml]);
        float fi = __bfloat162float(Fpk[slab + (size_t)(i + N_ST) * 16 + ml]);
        float nre = dr * re - di * im + fr;
        float nim = dr * im + di * re + fi;
        re = nre; im = nim;
        Zpk[slab + (size_t)i * 16 + ml]          = __float2bfloat16(re);
        Zpk[slab + (size_t)(i + N_ST) * 16 + ml] = __float2bfloat16(im);
    }
}

__global__ void copy_t0(const float* __restrict__ xi0, float* __restrict__ out) {
    int b = blockIdx.x, j = threadIdx.x;   // 16 x 512
    out[(size_t)b * TSTEPS * TWO_N + j] = xi0[b * TWO_N + j];
}

extern "C" void kernel_launch(void* const* d_in, const int* in_sizes, int n_in,
                              void* d_out, int out_size, void* d_ws, size_t ws_size,
                              hipStream_t stream) {
    const float* xi_init = (const float*)d_in[0];
    const float* u_log   = (const float*)d_in[1];
    const float* alpha   = (const float*)d_in[2];
    const float* theta   = (const float*)d_in[3];
    const float* B_re    = (const float*)d_in[4];
    const float* B_im    = (const float*)d_in[5];
    const float* P_re    = (const float*)d_in[6];
    const float* P_im    = (const float*)d_in[7];
    const float* Pinv_re = (const float*)d_in[8];
    const float* Pinv_im = (const float*)d_in[9];
    float* out = (float*)d_out;
    float* ws  = (float*)d_ws;

    __hip_bfloat16* Fpk  = (__hip_bfloat16*)(ws + OFF_FPK);
    __hip_bfloat16* Zpk  = (__hip_bfloat16*)(ws + OFF_ZPK);
    __hip_bfloat16* upk  = (__hip_bfloat16*)(ws + OFF_UPK);
    __hip_bfloat16* Wtpk = (__hip_bfloat16*)(ws + OFF_WT);
    __hip_bfloat16* Wfpk = (__hip_bfloat16*)(ws + OFF_WF);
    float* dbuf  = ws + OFF_D;
    float* xbar0 = ws + OFF_XBAR0;
    float* e     = ws + OFF_E;
    float* cinit = ws + OFF_CINIT;

    prep_W<<<1024, 256, 0, stream>>>(P_re, P_im, Wtpk);
    prep_Wf<<<256, 256, 0, stream>>>(B_re, B_im, Wfpk);
    prep_d<<<1, 256, 0, stream>>>(alpha, theta, dbuf);
    xbar0_kernel<<<16, 256, 0, stream>>>(Pinv_re, Pinv_im, xi_init, xbar0);
    upack<<<(MTOT * NU) / 256, 256, 0, stream>>>(u_log, upk);

    // forcing (packed bf16 out): F = h * u @ Bc^T
    gemm_mfma<NU, true><<<dim3(MTOT / 128, 4), 256, 0, stream>>>(
        (const short*)upk, (const short*)Wfpk, nullptr, (short*)Fpk);

    // chunked diagonal scan (32 chunks of 64 steps)
    scan_passA<<<dim3(BATCH, NCHUNK), 256, 0, stream>>>(Fpk, dbuf, e);
    scan_passB<<<BATCH, 256, 0, stream>>>(e, dbuf, xbar0, cinit);
    scan_passC<<<dim3(BATCH, NCHUNK), 256, 0, stream>>>(Fpk, dbuf, cinit, Zpk);

    // output projection: out = Z @ W^T (f32 out)
    gemm_mfma<TWO_N, false><<<dim3(MTOT / 128, 4), 256, 0, stream>>>(
        (const short*)Zpk, (const short*)Wtpk, out, nullptr);

    copy_t0<<<BATCH, TWO_N, 0, stream>>>(xi_init, out);
}

// Round 4
// 130.894 us; speedup vs baseline: 2.7832x; 1.0122x over previous
//
#include <hip/hip_runtime.h>
#include <hip/hip_bf16.h>
#include <cstddef>
#include <cstdint>

#define N_ST 256
#define TWO_N 512
#define NU 128
#define BATCH 16
#define TSTEPS 2048
#define MTOT (BATCH * TSTEPS)   // 32768
#define H_STEP 0.01f
#define EPS_V 0.001f
#define NCHUNK 32
#define CHUNKL 64
#define NBLK (MTOT / CHUNKL)    // 512 chunk-blocks

typedef __attribute__((ext_vector_type(4))) float f32x4;
typedef __attribute__((ext_vector_type(4))) short s16x4;
typedef __attribute__((ext_vector_type(8))) short s16x8;

// ---- workspace layout (float offsets) ----
#define OFF_UPK    0            // 4194304 shorts: packed bf16 u [(m>>4)][k=128][m&15]
#define OFF_WT     2097152      // 262144 shorts: packed Wt [(n>>4)][k=512][n&15]
#define OFF_WF     2228224      // 65536 shorts: packed Wf [(c>>4)][k=128][c&15]
#define OFF_D      2260992      // 1024 f32
#define OFF_XBAR0  2262016      // 8192 f32
#define OFF_E      2270208      // 512*512 f32
#define OFF_CINIT  2532352      // 512*512 f32

// ---- LDS map (bytes) for chunk kernel ----
#define LDS_A 0                 // 16 KB: packed u-chunk [4 slabs][128 k][16]
#define LDS_F 16384             // 64 KB: F/Z natural [64 t][512 s] bf16, XOR-swizzled
#define LDS_B 81920             // 64 KB: B double buffer (2 x 32 KB)
#define LDS_TOTAL 147456        // 144 KB

// swizzle: byte(t,s) = t*1024 + ((s*2) ^ ((t&15)<<3))

// ---- precompute kernels ----

__global__ void prep_W(const float* __restrict__ P_re, const float* __restrict__ P_im,
                       __hip_bfloat16* __restrict__ Wtpk) {
    int idx = blockIdx.x * blockDim.x + threadIdx.x;   // 262144
    int j = idx >> 9;          // output dim (n)
    int c = idx & 511;         // state dim (k)
    float v;
    if (c < N_ST) v = P_re[j * TWO_N + c] + P_re[j * TWO_N + c + N_ST];
    else          v = P_im[j * TWO_N + c] - P_im[j * TWO_N + c - N_ST];
    Wtpk[((size_t)(j >> 4) * TWO_N + c) * 16 + (j & 15)] = __float2bfloat16(v);
}

__global__ void prep_Wf(const float* __restrict__ B_re, const float* __restrict__ B_im,
                        __hip_bfloat16* __restrict__ Wfpk) {
    int idx = blockIdx.x * blockDim.x + threadIdx.x;   // 65536
    int k = idx >> 9;          // input dim (k)
    int c = idx & 511;         // state dim (n)
    float v = (c < N_ST) ? B_re[c * NU + k] : B_im[(c - N_ST) * NU + k];
    Wfpk[((size_t)(c >> 4) * NU + k) * 16 + (c & 15)] = __float2bfloat16(H_STEP * v);
}

// coalesced u -> packed bf16 via LDS transpose
__global__ __launch_bounds__(256) void upack(const float* __restrict__ u, short* __restrict__ upk) {
    __shared__ short st[64 * 132];
    int tid = threadIdx.x, bid = blockIdx.x;   // 512 blocks: 64 m x 128 k each
    const float* up = u + (size_t)bid * 8192;
#pragma unroll
    for (int q = 0; q < 8; ++q) {
        int idx = q * 1024 + tid * 4;
        float4 v = *reinterpret_cast<const float4*>(up + idx);
        int m = idx >> 7, k = idx & 127;
        s16x4 pv;
        __hip_bfloat16 b0 = __float2bfloat16(v.x); pv[0] = *(short*)&b0;
        __hip_bfloat16 b1 = __float2bfloat16(v.y); pv[1] = *(short*)&b1;
        __hip_bfloat16 b2 = __float2bfloat16(v.z); pv[2] = *(short*)&b2;
        __hip_bfloat16 b3 = __float2bfloat16(v.w); pv[3] = *(short*)&b3;
        *reinterpret_cast<__shared__ s16x4*>(&st[m * 132 + k]) = pv;
    }
    __syncthreads();
    short* op = upk + (size_t)bid * 8192;
#pragma unroll
    for (int q2 = 0; q2 < 4; ++q2) {
        int o = q2 * 2048 + tid * 8;
        int ml = o & 15, k = (o >> 4) & 127, sl = o >> 11;
        s16x8 w;
#pragma unroll
        for (int r = 0; r < 8; ++r) w[r] = st[(sl * 16 + ml + r) * 132 + k];
        *reinterpret_cast<s16x8*>(op + o) = w;
    }
}

__global__ void prep_d(const float* __restrict__ alpha, const float* __restrict__ theta,
                       float* __restrict__ dbuf) {
    int i = threadIdx.x;       // 256
    float dr = 1.0f + H_STEP * (-expf(alpha[i]) - EPS_V);
    float di = H_STEP * theta[i];
    float pr = 1.0f, pi = 0.0f;
    for (int k = 0; k < CHUNKL; ++k) { float nr = pr * dr - pi * di; pi = pr * di + pi * dr; pr = nr; }
    dbuf[i] = dr; dbuf[N_ST + i] = di; dbuf[2 * N_ST + i] = pr; dbuf[3 * N_ST + i] = pi;
}

__global__ void xbar0_kernel(const float* __restrict__ Pinv_re, const float* __restrict__ Pinv_im,
                             const float* __restrict__ xi0, float* __restrict__ xbar0) {
    int b = blockIdx.x; int i = threadIdx.x;   // 16 x 256
    __shared__ float xs[TWO_N];
    for (int j = threadIdx.x; j < TWO_N; j += blockDim.x) xs[j] = xi0[b * TWO_N + j];
    __syncthreads();
    float re = 0.f, im = 0.f;
    for (int j = 0; j < TWO_N; ++j) {
        float x = xs[j];
        re += Pinv_re[i * TWO_N + j] * x;
        im += Pinv_im[i * TWO_N + j] * x;
    }
    xbar0[b * TWO_N + i] = re;
    xbar0[b * TWO_N + N_ST + i] = im;
}

// ---- fused chunk kernel ----
// Phase 1: F (64x512) = upk_chunk @ Wfpk^T via MFMA, K=128, into swizzled LDS.
// Phase 2: diagonal scan over 64 steps (thread = complex state).
//   FULL=false: init 0, write end-state to e, done.
//   FULL=true : init from cinit, write Z back into LDS in place, then
// Phase 3: out (64x512) = Z @ Wtpk^T via MFMA, K=512, 2-phase B prefetch.
template <bool FULL>
__global__ __launch_bounds__(256, 1) void chunk_kernel(
    const short* __restrict__ upk, const short* __restrict__ Wfpk,
    const short* __restrict__ Wtpk, const float* __restrict__ dbuf,
    const float* __restrict__ cinit, float* __restrict__ e,
    float* __restrict__ out)
{
    extern __shared__ char smem[];
    const int tid = threadIdx.x;
    const int wv = tid >> 6, lane = tid & 63;
    const int laneL = lane & 15, laneH = lane >> 4;
    const int bid = blockIdx.x;    // 0..511 ; chunk rows m in [bid*64, bid*64+64)
    const unsigned ldsAddr = (unsigned)(uintptr_t)(__attribute__((address_space(3))) char*)&smem[0];

    // ---------- Phase 1 ----------
    // stage A (whole u-chunk, 16 KB): wave wv -> slab wv, quarters q
#pragma unroll
    for (int q = 0; q < 4; ++q) {
        const short* src = upk + ((size_t)(bid * 4 + wv) * NU + q * 32) * 16 + lane * 8;
        __builtin_amdgcn_global_load_lds((const __attribute__((address_space(1))) void*)src,
            (__attribute__((address_space(3))) void*)(smem + LDS_A + wv * 4096 + q * 1024), 16, 0, 0);
    }
#define STAGE_B1(sb, buf)                                                                           \
    do {                                                                                            \
        for (int jj = 0; jj < 2; ++jj) {                                                            \
            int j_ = wv * 2 + jj;                                                                   \
            for (int q_ = 0; q_ < 4; ++q_) {                                                        \
                const short* src_ = Wfpk + ((size_t)((sb) * 8 + j_) * NU + q_ * 32) * 16 + lane * 8; \
                __builtin_amdgcn_global_load_lds((const __attribute__((address_space(1))) void*)src_,\
                    (__attribute__((address_space(3))) void*)(smem + LDS_B + (buf) * 32768 + j_ * 4096 + q_ * 1024), 16, 0, 0); \
            }                                                                                       \
        }                                                                                           \
    } while (0)

    STAGE_B1(0, 0);
    asm volatile("s_waitcnt vmcnt(0)" ::: "memory");
    __syncthreads();

    // preload A fragments for all 4 K-steps (register-resident for phase 1)
    s16x8 av1[4];
    {
        s16x4 lo[4], hi[4];
#pragma unroll
        for (int K4 = 0; K4 < 4; ++K4) {
            unsigned ad = ldsAddr + LDS_A + wv * 4096 + K4 * 1024 + lane * 8;
            asm volatile("ds_read_b64_tr_b16 %0, %1 offset:0"   : "=v"(lo[K4]) : "v"(ad));
            asm volatile("ds_read_b64_tr_b16 %0, %1 offset:512" : "=v"(hi[K4]) : "v"(ad));
        }
        asm volatile("s_waitcnt lgkmcnt(0)" ::: "memory");
        __builtin_amdgcn_sched_barrier(0);
#pragma unroll
        for (int K4 = 0; K4 < 4; ++K4)
            av1[K4] = __builtin_shufflevector(lo[K4], hi[K4], 0, 1, 2, 3, 4, 5, 6, 7);
    }

    for (int sb = 0; sb < 4; ++sb) {
        int buf = sb & 1;
        if (sb < 3) STAGE_B1(sb + 1, buf ^ 1);
        f32x4 acc8[8] = {};
#pragma unroll
        for (int K4 = 0; K4 < 4; ++K4) {
            s16x4 blo[8], bhi[8];
#pragma unroll
            for (int j = 0; j < 8; ++j) {
                unsigned bd = ldsAddr + LDS_B + buf * 32768 + j * 4096 + K4 * 1024 + lane * 8;
                asm volatile("ds_read_b64_tr_b16 %0, %1 offset:0"   : "=v"(blo[j]) : "v"(bd));
                asm volatile("ds_read_b64_tr_b16 %0, %1 offset:512" : "=v"(bhi[j]) : "v"(bd));
            }
            asm volatile("s_waitcnt lgkmcnt(0)" ::: "memory");
            __builtin_amdgcn_sched_barrier(0);
#pragma unroll
            for (int j = 0; j < 8; ++j) {
                s16x8 bv = __builtin_shufflevector(blo[j], bhi[j], 0, 1, 2, 3, 4, 5, 6, 7);
                acc8[j] = __builtin_amdgcn_mfma_f32_16x16x32_bf16(av1[K4], bv, acc8[j], 0, 0, 0);
            }
        }
        // write F tile: t = wv*16 + laneH*4 + r ; s = sb*128 + j*16 + laneL
#pragma unroll
        for (int j = 0; j < 8; ++j) {
            int s = sb * 128 + j * 16 + laneL;
#pragma unroll
            for (int r = 0; r < 4; ++r) {
                int t = wv * 16 + laneH * 4 + r;
                __hip_bfloat16 b = __float2bfloat16(acc8[j][r]);
                *(short*)(smem + LDS_F + t * 1024 + (((unsigned)(s * 2)) ^ (unsigned)((t & 15) << 3))) = *(short*)&b;
            }
        }
        asm volatile("s_waitcnt vmcnt(0)" ::: "memory");
        __syncthreads();
    }
#undef STAGE_B1

    // prologue for phase 3: stage Wt K-step 0 into buf0 (latency hidden by scan)
    if (FULL) {
#pragma unroll
        for (int j = 0; j < 8; ++j) {
            int sp = wv * 8 + j;
            const short* src = Wtpk + (size_t)sp * 8192 + lane * 8;
            __builtin_amdgcn_global_load_lds((const __attribute__((address_space(1))) void*)src,
                (__attribute__((address_space(3))) void*)(smem + LDS_B + sp * 1024), 16, 0, 0);
        }
    }

    // ---------- Phase 2: diagonal scan ----------
    {
        const int i2 = tid;   // complex state 0..255
        float dr = dbuf[i2], di = dbuf[N_ST + i2];
        float re, im;
        if (FULL) { re = cinit[(size_t)bid * TWO_N + i2]; im = cinit[(size_t)bid * TWO_N + N_ST + i2]; }
        else      { re = 0.f; im = 0.f; }
        const unsigned colr = (unsigned)(2 * i2);
#pragma unroll 8
        for (int t = 0; t < CHUNKL; ++t) {
            char* p = smem + LDS_F + t * 1024 + (colr ^ (unsigned)((t & 15) << 3));
            unsigned short ur = *(unsigned short*)p;
            unsigned short ui = *(unsigned short*)(p + 512);
            float fr = __uint_as_float(((unsigned)ur) << 16);
            float fi = __uint_as_float(((unsigned)ui) << 16);
            float nre = fmaf(dr, re, fmaf(-di, im, fr));
            float nim = fmaf(dr, im, fmaf(di, re, fi));
            re = nre; im = nim;
            if (FULL) {
                __hip_bfloat16 br = __float2bfloat16(re), bi = __float2bfloat16(im);
                *(short*)p = *(short*)&br;
                *(short*)(p + 512) = *(short*)&bi;
            }
        }
        if (!FULL) {
            e[(size_t)bid * TWO_N + i2] = re;
            e[(size_t)bid * TWO_N + N_ST + i2] = im;
            return;
        }
    }
    asm volatile("s_waitcnt vmcnt(0)" ::: "memory");
    __syncthreads();   // Z published; Wt buf0 resident

    // ---------- Phase 3: out = Z @ Wt^T, K=512, 16 K-steps, 2-phase ----------
    const int m0 = bid * 64;
    f32x4 acc[4][8] = {};
    for (int ks = 0; ks < 16; ++ks) {
        const int KK = ks * 32;
        const int buf = ks & 1;
        if (ks < 15) {
#pragma unroll
            for (int j = 0; j < 8; ++j) {
                int sp = wv * 8 + j;
                const short* src = Wtpk + (size_t)sp * 8192 + (size_t)(KK + 32) * 16 + lane * 8;
                __builtin_amdgcn_global_load_lds((const __attribute__((address_space(1))) void*)src,
                    (__attribute__((address_space(3))) void*)(smem + LDS_B + (buf ^ 1) * 32768 + sp * 1024), 16, 0, 0);
            }
        }
        // A-fragments from swizzled Z (plain ds_read_b64 pairs)
        s16x8 av[4];
        {
            const unsigned klo = (unsigned)((KK + laneH * 4) * 2);
            const unsigned swz = (unsigned)(laneL << 3);   // (row&15)<<3, row = i*16+laneL
#pragma unroll
            for (int i = 0; i < 4; ++i) {
                char* base = smem + LDS_F + (i * 16 + laneL) * 1024;
                s16x4 lo = *(s16x4*)(base + (klo ^ swz));
                s16x4 hi = *(s16x4*)(base + ((klo + 32) ^ swz));
                av[i] = __builtin_shufflevector(lo, hi, 0, 1, 2, 3, 4, 5, 6, 7);
            }
        }
        // B-fragments (tr-read) + MFMA
        s16x4 blo[8], bhi[8];
#pragma unroll
        for (int j = 0; j < 8; ++j) {
            unsigned bd = ldsAddr + LDS_B + buf * 32768 + (wv * 8 + j) * 1024 + lane * 8;
            asm volatile("ds_read_b64_tr_b16 %0, %1 offset:0"   : "=v"(blo[j]) : "v"(bd));
            asm volatile("ds_read_b64_tr_b16 %0, %1 offset:512" : "=v"(bhi[j]) : "v"(bd));
        }
        asm volatile("s_waitcnt lgkmcnt(0)" ::: "memory");
        __builtin_amdgcn_sched_barrier(0);
#pragma unroll
        for (int j = 0; j < 8; ++j) {
            s16x8 bv = __builtin_shufflevector(blo[j], bhi[j], 0, 1, 2, 3, 4, 5, 6, 7);
#pragma unroll
            for (int i = 0; i < 4; ++i)
                acc[i][j] = __builtin_amdgcn_mfma_f32_16x16x32_bf16(av[i], bv, acc[i][j], 0, 0, 0);
        }
        asm volatile("s_waitcnt vmcnt(0)" ::: "memory");
        __syncthreads();
    }
    // epilogue: out rows m0 + i*16 + laneH*4 + r, cols wv*128 + j*16 + laneL
#pragma unroll
    for (int i = 0; i < 4; ++i) {
#pragma unroll
        for (int r = 0; r < 4; ++r) {
            float* cp = out + (size_t)(m0 + i * 16 + laneH * 4 + r) * TWO_N + wv * 128 + laneL;
#pragma unroll
            for (int j = 0; j < 8; ++j) cp[j * 16] = acc[i][j][r];
        }
    }
}

// ---- sequential chunk combine ----
__global__ void scan_passB(const float* __restrict__ e, const float* __restrict__ dbuf,
                           const float* __restrict__ xbar0, float* __restrict__ cinit) {
    int b = blockIdx.x, i = threadIdx.x;
    float dLr = dbuf[2 * N_ST + i], dLi = dbuf[3 * N_ST + i];
    float re = xbar0[b * TWO_N + i], im = xbar0[b * TWO_N + N_ST + i];
    for (int c = 0; c < NCHUNK; ++c) {
        size_t o = ((size_t)(b * NCHUNK + c)) * TWO_N;
        cinit[o + i] = re;
        cinit[o + N_ST + i] = im;
        float er = e[o + i], ei = e[o + N_ST + i];
        float nre = dLr * re - dLi * im + er;
        float nim = dLr * im + dLi * re + ei;
        re = nre; im = nim;
    }
}

__global__ void copy_t0(const float* __restrict__ xi0, float* __restrict__ out) {
    int b = blockIdx.x, j = threadIdx.x;   // 16 x 512
    out[(size_t)b * TSTEPS * TWO_N + j] = xi0[b * TWO_N + j];
}

extern "C" void kernel_launch(void* const* d_in, const int* in_sizes, int n_in,
                              void* d_out, int out_size, void* d_ws, size_t ws_size,
                              hipStream_t stream) {
    const float* xi_init = (const float*)d_in[0];
    const float* u_log   = (const float*)d_in[1];
    const float* alpha   = (const float*)d_in[2];
    const float* theta   = (const float*)d_in[3];
    const float* B_re    = (const float*)d_in[4];
    const float* B_im    = (const float*)d_in[5];
    const float* P_re    = (const float*)d_in[6];
    const float* P_im    = (const float*)d_in[7];
    const float* Pinv_re = (const float*)d_in[8];
    const float* Pinv_im = (const float*)d_in[9];
    float* out = (float*)d_out;
    float* ws  = (float*)d_ws;

    short* upk  = (short*)(ws + OFF_UPK);
    short* Wtpk = (short*)(ws + OFF_WT);
    short* Wfpk = (short*)(ws + OFF_WF);
    float* dbuf  = ws + OFF_D;
    float* xbar0 = ws + OFF_XBAR0;
    float* e     = ws + OFF_E;
    float* cinit = ws + OFF_CINIT;

    // raise dynamic-LDS cap (skip while capturing; attribute persists from eager call)
    hipStreamCaptureStatus cst = hipStreamCaptureStatusNone;
    hipError_t qerr = hipStreamIsCapturing(stream, &cst);
    if (qerr != hipSuccess || cst == hipStreamCaptureStatusNone) {
        (void)hipFuncSetAttribute(reinterpret_cast<const void*>(chunk_kernel<false>),
                                  hipFuncAttributeMaxDynamicSharedMemorySize, LDS_TOTAL);
        (void)hipFuncSetAttribute(reinterpret_cast<const void*>(chunk_kernel<true>),
                                  hipFuncAttributeMaxDynamicSharedMemorySize, LDS_TOTAL);
    }

    prep_W<<<1024, 256, 0, stream>>>(P_re, P_im, (__hip_bfloat16*)Wtpk);
    prep_Wf<<<256, 256, 0, stream>>>(B_re, B_im, (__hip_bfloat16*)Wfpk);
    prep_d<<<1, 256, 0, stream>>>(alpha, theta, dbuf);
    xbar0_kernel<<<16, 256, 0, stream>>>(Pinv_re, Pinv_im, xi_init, xbar0);
    upack<<<NBLK, 256, 0, stream>>>(u_log, upk);

    // K1: forcing + chunk-local scan -> e
    chunk_kernel<false><<<NBLK, 256, LDS_TOTAL, stream>>>(upk, Wfpk, Wtpk, dbuf, nullptr, e, nullptr);

    // sequential combine across chunks
    scan_passB<<<BATCH, 256, 0, stream>>>(e, dbuf, xbar0, cinit);

    // K3: forcing + scan from cinit + output projection
    chunk_kernel<true><<<NBLK, 256, LDS_TOTAL, stream>>>(upk, Wfpk, Wtpk, dbuf, cinit, nullptr, out);

    copy_t0<<<BATCH, TWO_N, 0, stream>>>(xi_init, out);
}

// Round 5
// 100.891 us; speedup vs baseline: 3.6109x; 1.2974x over previous
//
#include <hip/hip_runtime.h>
#include <hip/hip_bf16.h>
#include <cstddef>
#include <cstdint>

#define N_ST 256
#define TWO_N 512
#define NU 128
#define BATCH 16
#define TSTEPS 2048
#define MTOT (BATCH * TSTEPS)   // 32768
#define H_STEP 0.01f
#define EPS_V 0.001f
#define NCHUNK 32
#define CHUNKL 64

typedef __attribute__((ext_vector_type(4))) float f32x4;
typedef __attribute__((ext_vector_type(4))) short s16x4;
typedef __attribute__((ext_vector_type(8))) short s16x8;

// ---- workspace layout (float offsets) ----
#define OFF_FPK    0            // 16777216 shorts: packed bf16 F [(m>>4)][k=512][m&15]
#define OFF_ZPK    8388608      // 16777216 shorts: packed bf16 Z, same layout
#define OFF_UPK    16777216     // 4194304 shorts: packed bf16 u [(m>>4)][k=128][m&15]
#define OFF_WT     18874368     // 262144 shorts
#define OFF_WF     19005440     // 65536 shorts
#define OFF_D      19038208     // 1024 f32
#define OFF_XBAR0  19039232     // 8192 f32
#define OFF_E      19047424     // 512*512 f32
#define OFF_CINIT  19309568     // 512*512 f32

static __device__ __forceinline__ float bf2f(short s) {
    return __uint_as_float(((unsigned)(unsigned short)s) << 16);
}

// ---- fused precompute: blocks 0..1023 prep_W, 1024..1279 prep_Wf, 1280 prep_d, 1281..1296 xbar0
__global__ __launch_bounds__(256) void prep_all(
    const float* __restrict__ P_re, const float* __restrict__ P_im,
    const float* __restrict__ B_re, const float* __restrict__ B_im,
    const float* __restrict__ alpha, const float* __restrict__ theta,
    const float* __restrict__ Pinv_re, const float* __restrict__ Pinv_im,
    const float* __restrict__ xi0,
    short* __restrict__ Wtpk, short* __restrict__ Wfpk,
    float* __restrict__ dbuf, float* __restrict__ xbar0)
{
    __shared__ float xs[TWO_N];
    int blk = blockIdx.x, tid = threadIdx.x;
    if (blk < 1024) {
        int idx = blk * 256 + tid;
        int j = idx >> 9, c = idx & 511;
        float v;
        if (c < N_ST) v = P_re[j * TWO_N + c] + P_re[j * TWO_N + c + N_ST];
        else          v = P_im[j * TWO_N + c] - P_im[j * TWO_N + c - N_ST];
        __hip_bfloat16 b = __float2bfloat16(v);
        Wtpk[((size_t)(j >> 4) * TWO_N + c) * 16 + (j & 15)] = *(short*)&b;
    } else if (blk < 1280) {
        int idx = (blk - 1024) * 256 + tid;
        int k = idx >> 9, c = idx & 511;
        float v = (c < N_ST) ? B_re[c * NU + k] : B_im[(c - N_ST) * NU + k];
        __hip_bfloat16 b = __float2bfloat16(H_STEP * v);
        Wfpk[((size_t)(c >> 4) * NU + k) * 16 + (c & 15)] = *(short*)&b;
    } else if (blk == 1280) {
        int i = tid;
        float dr = 1.0f + H_STEP * (-expf(alpha[i]) - EPS_V);
        float di = H_STEP * theta[i];
        float pr = 1.0f, pi = 0.0f;
        for (int k = 0; k < CHUNKL; ++k) { float nr = pr * dr - pi * di; pi = pr * di + pi * dr; pr = nr; }
        dbuf[i] = dr; dbuf[N_ST + i] = di; dbuf[2 * N_ST + i] = pr; dbuf[3 * N_ST + i] = pi;
    } else {
        int b = blk - 1281, i = tid;
        for (int j = tid; j < TWO_N; j += 256) xs[j] = xi0[b * TWO_N + j];
        __syncthreads();
        float re = 0.f, im = 0.f;
        for (int j = 0; j < TWO_N; ++j) {
            float x = xs[j];
            re += Pinv_re[i * TWO_N + j] * x;
            im += Pinv_im[i * TWO_N + j] * x;
        }
        xbar0[b * TWO_N + i] = re;
        xbar0[b * TWO_N + N_ST + i] = im;
    }
}

// coalesced u -> packed bf16 via LDS transpose
__global__ __launch_bounds__(256) void upack(const float* __restrict__ u, short* __restrict__ upk) {
    __shared__ short st[64 * 132];
    int tid = threadIdx.x, bid = blockIdx.x;   // 512 blocks: 64 m x 128 k each
    const float* up = u + (size_t)bid * 8192;
#pragma unroll
    for (int q = 0; q < 8; ++q) {
        int idx = q * 1024 + tid * 4;
        float4 v = *reinterpret_cast<const float4*>(up + idx);
        int m = idx >> 7, k = idx & 127;
        s16x4 pv;
        __hip_bfloat16 b0 = __float2bfloat16(v.x); pv[0] = *(short*)&b0;
        __hip_bfloat16 b1 = __float2bfloat16(v.y); pv[1] = *(short*)&b1;
        __hip_bfloat16 b2 = __float2bfloat16(v.z); pv[2] = *(short*)&b2;
        __hip_bfloat16 b3 = __float2bfloat16(v.w); pv[3] = *(short*)&b3;
        *reinterpret_cast<__shared__ s16x4*>(&st[m * 132 + k]) = pv;
    }
    __syncthreads();
    short* op = upk + (size_t)bid * 8192;
#pragma unroll
    for (int q2 = 0; q2 < 4; ++q2) {
        int o = q2 * 2048 + tid * 8;
        int ml = o & 15, k = (o >> 4) & 127, sl = o >> 11;
        s16x8 w;
#pragma unroll
        for (int r = 0; r < 8; ++r) w[r] = st[(sl * 16 + ml + r) * 132 + k];
        *reinterpret_cast<s16x8*>(op + o) = w;
    }
}

// ---- bf16 MFMA GEMM, 2-phase pipelined, 128x128 tile, 4 waves.
// Apk/Bpk packed: elem(row,k) at [(row>>4)*K + k]*16 + (row&15).
// PACKOUT=false: write f32 C[M][512], with xi0 fold for t==0 rows.
// PACKOUT=true: write packed bf16 (forcing).
template <int K, bool PACKOUT>
__global__ __launch_bounds__(256, 2) void gemm_mfma(const short* __restrict__ Apk,
                                                    const short* __restrict__ Bpk,
                                                    float* __restrict__ Cf,
                                                    short* __restrict__ Cp,
                                                    const float* __restrict__ xi0) {
    __shared__ __align__(1024) short lds[16384];   // A: [buf]*4096, B: 8192+[buf]*4096
    const int tid = threadIdx.x;
    const int wid = tid >> 6, lane = tid & 63;
    const int m0 = blockIdx.x * 128, n0 = blockIdx.y * 128;
    const int wm = wid >> 1, wn = wid & 1;
    f32x4 acc[4][4] = {};
    const size_t slabStride = (size_t)K * 16;
    const unsigned ldsBase = (unsigned)(uintptr_t)(__attribute__((address_space(3))) short*)&lds[0];

#define STAGE(buf, kk)                                                                              \
    do {                                                                                            \
        const short* gA0 = Apk + ((size_t)(m0 >> 4) + wid)     * slabStride + (size_t)(kk) * 16 + lane * 8; \
        const short* gA1 = Apk + ((size_t)(m0 >> 4) + wid + 4) * slabStride + (size_t)(kk) * 16 + lane * 8; \
        const short* gB0 = Bpk + ((size_t)(n0 >> 4) + wid)     * slabStride + (size_t)(kk) * 16 + lane * 8; \
        const short* gB1 = Bpk + ((size_t)(n0 >> 4) + wid + 4) * slabStride + (size_t)(kk) * 16 + lane * 8; \
        __builtin_amdgcn_global_load_lds((const __attribute__((address_space(1))) void*)gA0,        \
            (__attribute__((address_space(3))) void*)&lds[(buf) * 4096 + wid * 512], 16, 0, 0);     \
        __builtin_amdgcn_global_load_lds((const __attribute__((address_space(1))) void*)gA1,        \
            (__attribute__((address_space(3))) void*)&lds[(buf) * 4096 + (wid + 4) * 512], 16, 0, 0); \
        __builtin_amdgcn_global_load_lds((const __attribute__((address_space(1))) void*)gB0,        \
            (__attribute__((address_space(3))) void*)&lds[8192 + (buf) * 4096 + wid * 512], 16, 0, 0); \
        __builtin_amdgcn_global_load_lds((const __attribute__((address_space(1))) void*)gB1,        \
            (__attribute__((address_space(3))) void*)&lds[8192 + (buf) * 4096 + (wid + 4) * 512], 16, 0, 0); \
    } while (0)

    STAGE(0, 0);
    asm volatile("s_waitcnt vmcnt(0)" ::: "memory");
    __syncthreads();
    int cur = 0;
    for (int kk = 0; kk < K; kk += 32) {
        if (kk + 32 < K) STAGE(cur ^ 1, kk + 32);   // prefetch next tile under current compute

        s16x4 al[4], ah[4], bl[4], bh[4];
        const unsigned aB = ldsBase + (unsigned)cur * 8192;
        const unsigned bB = ldsBase + 16384u + (unsigned)cur * 8192;
#pragma unroll
        for (int t = 0; t < 4; ++t) {
            unsigned ad = aB + ((unsigned)(wm * 4 + t) << 10) + ((unsigned)lane << 3);
            unsigned bd = bB + ((unsigned)(wn * 4 + t) << 10) + ((unsigned)lane << 3);
            asm volatile("ds_read_b64_tr_b16 %0, %1 offset:0"   : "=v"(al[t]) : "v"(ad));
            asm volatile("ds_read_b64_tr_b16 %0, %1 offset:512" : "=v"(ah[t]) : "v"(ad));
            asm volatile("ds_read_b64_tr_b16 %0, %1 offset:0"   : "=v"(bl[t]) : "v"(bd));
            asm volatile("ds_read_b64_tr_b16 %0, %1 offset:512" : "=v"(bh[t]) : "v"(bd));
        }
        asm volatile("s_waitcnt lgkmcnt(0)" ::: "memory");
        __builtin_amdgcn_sched_barrier(0);   // rule 18

#pragma unroll
        for (int i = 0; i < 4; ++i) {
            s16x8 av = __builtin_shufflevector(al[i], ah[i], 0, 1, 2, 3, 4, 5, 6, 7);
#pragma unroll
            for (int j = 0; j < 4; ++j) {
                s16x8 bv = __builtin_shufflevector(bl[j], bh[j], 0, 1, 2, 3, 4, 5, 6, 7);
                acc[i][j] = __builtin_amdgcn_mfma_f32_16x16x32_bf16(av, bv, acc[i][j], 0, 0, 0);
            }
        }
        asm volatile("s_waitcnt vmcnt(0)" ::: "memory");   // next tile's loads landed
        __syncthreads();
        cur ^= 1;
    }
#undef STAGE

    const int cn = lane & 15;
    const int g4 = (lane >> 4) * 4;
    if (!PACKOUT) {
        // C/D layout: col = lane&15, row = (lane>>4)*4 + reg  [m89]
#pragma unroll
        for (int i = 0; i < 4; ++i) {
            int mrow = m0 + (wm * 4 + i) * 16 + g4;
#pragma unroll
            for (int j = 0; j < 4; ++j) {
                int ncol = n0 + (wn * 4 + j) * 16 + cn;
                float* cp = Cf + (size_t)mrow * TWO_N + ncol;
#pragma unroll
                for (int r = 0; r < 4; ++r) {
                    float v = acc[i][j][r];
                    if (((mrow + r) & (TSTEPS - 1)) == 0)   // t==0 row: out = xi_init
                        v = xi0[((mrow + r) >> 11) * TWO_N + ncol];
                    cp[(size_t)r * TWO_N] = v;
                }
            }
        }
    } else {
        // build packed-bf16 tile image in LDS: [8 s][128 cwt][16 ml], 32 KB
#pragma unroll
        for (int i = 0; i < 4; ++i) {
            int s = wm * 4 + i;
#pragma unroll
            for (int j = 0; j < 4; ++j) {
                int cwt = wn * 64 + j * 16 + cn;
                s16x4 pv;
#pragma unroll
                for (int r = 0; r < 4; ++r) {
                    __hip_bfloat16 bb = __float2bfloat16(acc[i][j][r]);
                    pv[r] = *reinterpret_cast<short*>(&bb);
                }
                *reinterpret_cast<__shared__ s16x4*>(&lds[((s * 128 + cwt) << 4) + g4]) = pv;
            }
        }
        __syncthreads();
        size_t baseG = (size_t)(m0 >> 4) * ((size_t)TWO_N * 16) + (size_t)n0 * 16;
#pragma unroll
        for (int q = 0; q < 8; ++q) {
            *reinterpret_cast<s16x8*>(Cp + baseG + (size_t)q * (TWO_N * 16) + tid * 8) =
                *reinterpret_cast<const __shared__ s16x8*>(&lds[q * 2048 + tid * 8]);
        }
    }
}

// ---- vectorized chunked diagonal scan (packed layout: thread's data is contiguous) ----
__global__ __launch_bounds__(256) void scan_passA(const short* __restrict__ Fpk,
                                                  const float* __restrict__ dbuf,
                                                  float* __restrict__ e) {
    int b = blockIdx.x, c = blockIdx.y, i = threadIdx.x;   // i = complex state 0..255
    float dr = dbuf[i], di = dbuf[N_ST + i];
    float re = 0.f, im = 0.f;
    int slab0 = (b * TSTEPS + c * CHUNKL) >> 4;   // 4 slabs per chunk
#pragma unroll
    for (int g = 0; g < 4; ++g) {
        const short* base = Fpk + (size_t)(slab0 + g) * 8192 + i * 16;
        s16x8 r0 = *reinterpret_cast<const s16x8*>(base);
        s16x8 r1 = *reinterpret_cast<const s16x8*>(base + 8);
        s16x8 i0 = *reinterpret_cast<const s16x8*>(base + 4096);
        s16x8 i1 = *reinterpret_cast<const s16x8*>(base + 4096 + 8);
#pragma unroll
        for (int j = 0; j < 16; ++j) {
            float fr = bf2f(j < 8 ? r0[j & 7] : r1[j & 7]);
            float fi = bf2f(j < 8 ? i0[j & 7] : i1[j & 7]);
            float nre = fmaf(dr, re, fmaf(-di, im, fr));
            float nim = fmaf(dr, im, fmaf(di, re, fi));
            re = nre; im = nim;
        }
    }
    size_t o = ((size_t)(b * NCHUNK + c)) * TWO_N;
    e[o + i] = re;
    e[o + N_ST + i] = im;
}

__global__ void scan_passB(const float* __restrict__ e, const float* __restrict__ dbuf,
                           const float* __restrict__ xbar0, float* __restrict__ cinit) {
    int b = blockIdx.x, i = threadIdx.x;
    float dLr = dbuf[2 * N_ST + i], dLi = dbuf[3 * N_ST + i];
    float re = xbar0[b * TWO_N + i], im = xbar0[b * TWO_N + N_ST + i];
    for (int c = 0; c < NCHUNK; ++c) {
        size_t o = ((size_t)(b * NCHUNK + c)) * TWO_N;
        cinit[o + i] = re;
        cinit[o + N_ST + i] = im;
        float er = e[o + i], ei = e[o + N_ST + i];
        float nre = dLr * re - dLi * im + er;
        float nim = dLr * im + dLi * re + ei;
        re = nre; im = nim;
    }
}

__global__ __launch_bounds__(256) void scan_passC(const short* __restrict__ Fpk,
                                                  const float* __restrict__ dbuf,
                                                  const float* __restrict__ cinit,
                                                  short* __restrict__ Zpk) {
    int b = blockIdx.x, c = blockIdx.y, i = threadIdx.x;
    float dr = dbuf[i], di = dbuf[N_ST + i];
    size_t o = ((size_t)(b * NCHUNK + c)) * TWO_N;
    float re = cinit[o + i], im = cinit[o + N_ST + i];
    int slab0 = (b * TSTEPS + c * CHUNKL) >> 4;
#pragma unroll
    for (int g = 0; g < 4; ++g) {
        const short* base = Fpk + (size_t)(slab0 + g) * 8192 + i * 16;
        s16x8 r0 = *reinterpret_cast<const s16x8*>(base);
        s16x8 r1 = *reinterpret_cast<const s16x8*>(base + 8);
        s16x8 i0 = *reinterpret_cast<const s16x8*>(base + 4096);
        s16x8 i1 = *reinterpret_cast<const s16x8*>(base + 4096 + 8);
        s16x8 zr0, zr1, zi0, zi1;
#pragma unroll
        for (int j = 0; j < 16; ++j) {
            float fr = bf2f(j < 8 ? r0[j & 7] : r1[j & 7]);
            float fi = bf2f(j < 8 ? i0[j & 7] : i1[j & 7]);
            float nre = fmaf(dr, re, fmaf(-di, im, fr));
            float nim = fmaf(dr, im, fmaf(di, re, fi));
            re = nre; im = nim;
            __hip_bfloat16 br = __float2bfloat16(re), bi = __float2bfloat16(im);
            if (j < 8) { zr0[j & 7] = *(short*)&br; zi0[j & 7] = *(short*)&bi; }
            else       { zr1[j & 7] = *(short*)&br; zi1[j & 7] = *(short*)&bi; }
        }
        short* zb = Zpk + (size_t)(slab0 + g) * 8192 + i * 16;
        *reinterpret_cast<s16x8*>(zb)            = zr0;
        *reinterpret_cast<s16x8*>(zb + 8)        = zr1;
        *reinterpret_cast<s16x8*>(zb + 4096)     = zi0;
        *reinterpret_cast<s16x8*>(zb + 4096 + 8) = zi1;
    }
}

extern "C" void kernel_launch(void* const* d_in, const int* in_sizes, int n_in,
                              void* d_out, int out_size, void* d_ws, size_t ws_size,
                              hipStream_t stream) {
    const float* xi_init = (const float*)d_in[0];
    const float* u_log   = (const float*)d_in[1];
    const float* alpha   = (const float*)d_in[2];
    const float* theta   = (const float*)d_in[3];
    const float* B_re    = (const float*)d_in[4];
    const float* B_im    = (const float*)d_in[5];
    const float* P_re    = (const float*)d_in[6];
    const float* P_im    = (const float*)d_in[7];
    const float* Pinv_re = (const float*)d_in[8];
    const float* Pinv_im = (const float*)d_in[9];
    float* out = (float*)d_out;
    float* ws  = (float*)d_ws;

    short* Fpk  = (short*)(ws + OFF_FPK);
    short* Zpk  = (short*)(ws + OFF_ZPK);
    short* upk  = (short*)(ws + OFF_UPK);
    short* Wtpk = (short*)(ws + OFF_WT);
    short* Wfpk = (short*)(ws + OFF_WF);
    float* dbuf  = ws + OFF_D;
    float* xbar0 = ws + OFF_XBAR0;
    float* e     = ws + OFF_E;
    float* cinit = ws + OFF_CINIT;

    prep_all<<<1297, 256, 0, stream>>>(P_re, P_im, B_re, B_im, alpha, theta,
                                       Pinv_re, Pinv_im, xi_init, Wtpk, Wfpk, dbuf, xbar0);
    upack<<<MTOT / 64, 256, 0, stream>>>(u_log, upk);

    // forcing (packed bf16 out): F = h * u @ Bc^T
    gemm_mfma<NU, true><<<dim3(MTOT / 128, 4), 256, 0, stream>>>(
        upk, Wfpk, nullptr, Fpk, nullptr);

    // chunked diagonal scan (32 chunks of 64 steps)
    scan_passA<<<dim3(BATCH, NCHUNK), 256, 0, stream>>>(Fpk, dbuf, e);
    scan_passB<<<BATCH, 256, 0, stream>>>(e, dbuf, xbar0, cinit);
    scan_passC<<<dim3(BATCH, NCHUNK), 256, 0, stream>>>(Fpk, dbuf, cinit, Zpk);

    // output projection: out = Z @ W^T (f32 out, t==0 rows = xi_init folded in epilogue)
    gemm_mfma<TWO_N, false><<<dim3(MTOT / 128, 4), 256, 0, stream>>>(
        Zpk, Wtpk, out, nullptr, xi_init);
}

// Round 6
// 80.906 us; speedup vs baseline: 4.5028x; 1.2470x over previous
//
#include <hip/hip_runtime.h>
#include <hip/hip_bf16.h>
#include <cstddef>
#include <cstdint>

#define N_ST 256
#define TWO_N 512
#define NU 128
#define BATCH 16
#define TSTEPS 2048
#define MTOT (BATCH * TSTEPS)   // 32768
#define H_STEP 0.01f
#define EPS_V 0.001f
#define NCHUNK 32
#define CHUNKL 64

typedef __attribute__((ext_vector_type(4))) float f32x4;
typedef __attribute__((ext_vector_type(4))) short s16x4;
typedef __attribute__((ext_vector_type(8))) short s16x8;

// ---- workspace layout (float offsets) ----
#define OFF_FPK    0            // 16777216 shorts: packed bf16 F [(m>>4)][k=512][m&15]
#define OFF_ZPK    8388608      // 16777216 shorts: packed bf16 Z, same layout
#define OFF_UPK    16777216     // 4194304 shorts: packed bf16 u [(m>>4)][k=128][m&15]
#define OFF_WT     18874368     // 262144 shorts
#define OFF_WF     19005440     // 65536 shorts
#define OFF_D      19038208     // 1024 f32
#define OFF_XBAR0  19039232     // 8192 f32
#define OFF_E      19047424     // 512*512 f32
#define OFF_CINIT  19309568     // 512*512 f32

static __device__ __forceinline__ float bf2f(short s) {
    return __uint_as_float(((unsigned)(unsigned short)s) << 16);
}

// ---- fused precompute: blocks 0..1023 prep_W, 1024..1279 prep_Wf, 1280 prep_d
__global__ __launch_bounds__(256) void prep_all(
    const float* __restrict__ P_re, const float* __restrict__ P_im,
    const float* __restrict__ B_re, const float* __restrict__ B_im,
    const float* __restrict__ alpha, const float* __restrict__ theta,
    short* __restrict__ Wtpk, short* __restrict__ Wfpk,
    float* __restrict__ dbuf)
{
    int blk = blockIdx.x, tid = threadIdx.x;
    if (blk < 1024) {
        int idx = blk * 256 + tid;
        int j = idx >> 9, c = idx & 511;
        float v;
        if (c < N_ST) v = P_re[j * TWO_N + c] + P_re[j * TWO_N + c + N_ST];
        else          v = P_im[j * TWO_N + c] - P_im[j * TWO_N + c - N_ST];
        __hip_bfloat16 b = __float2bfloat16(v);
        Wtpk[((size_t)(j >> 4) * TWO_N + c) * 16 + (j & 15)] = *(short*)&b;
    } else if (blk < 1280) {
        int idx = (blk - 1024) * 256 + tid;
        int k = idx >> 9, c = idx & 511;
        float v = (c < N_ST) ? B_re[c * NU + k] : B_im[(c - N_ST) * NU + k];
        __hip_bfloat16 b = __float2bfloat16(H_STEP * v);
        Wfpk[((size_t)(c >> 4) * NU + k) * 16 + (c & 15)] = *(short*)&b;
    } else {
        int i = tid;
        float dr = 1.0f + H_STEP * (-expf(alpha[i]) - EPS_V);
        float di = H_STEP * theta[i];
        float pr = 1.0f, pi = 0.0f;
        for (int k = 0; k < CHUNKL; ++k) { float nr = pr * dr - pi * di; pi = pr * di + pi * dr; pr = nr; }
        dbuf[i] = dr; dbuf[N_ST + i] = di; dbuf[2 * N_ST + i] = pr; dbuf[3 * N_ST + i] = pi;
    }
}

// ---- xbar0: coalesced, wave-per-state. 64 blocks x 256 thr; wave w -> state i.
__global__ __launch_bounds__(256) void xbar0_kernel(
    const float* __restrict__ Pinv_re, const float* __restrict__ Pinv_im,
    const float* __restrict__ xi0, float* __restrict__ xbar0)
{
    __shared__ float xs[BATCH * TWO_N];   // 32 KB
    int tid = threadIdx.x;
#pragma unroll
    for (int q = 0; q < 8; ++q)
        *reinterpret_cast<float4*>(&xs[(q * 256 + tid) * 4]) =
            *reinterpret_cast<const float4*>(&xi0[(q * 256 + tid) * 4]);
    __syncthreads();

    int wv = tid >> 6, l = tid & 63;
    int i = blockIdx.x * 4 + wv;          // state 0..255
    float rp[BATCH] = {}, ip[BATCH] = {};
#pragma unroll
    for (int q = 0; q < 8; ++q) {
        int j = q * 64 + l;
        float pr = Pinv_re[(size_t)i * TWO_N + j];
        float pi = Pinv_im[(size_t)i * TWO_N + j];
#pragma unroll
        for (int b = 0; b < BATCH; ++b) {
            float x = xs[b * TWO_N + j];
            rp[b] = fmaf(pr, x, rp[b]);
            ip[b] = fmaf(pi, x, ip[b]);
        }
    }
#pragma unroll
    for (int m = 1; m < 64; m <<= 1) {
#pragma unroll
        for (int b = 0; b < BATCH; ++b) {
            rp[b] += __shfl_xor(rp[b], m, 64);
            ip[b] += __shfl_xor(ip[b], m, 64);
        }
    }
    if (l == 0) {
#pragma unroll
        for (int b = 0; b < BATCH; ++b) {
            xbar0[b * TWO_N + i] = rp[b];
            xbar0[b * TWO_N + N_ST + i] = ip[b];
        }
    }
}

// coalesced u -> packed bf16 via LDS transpose
__global__ __launch_bounds__(256) void upack(const float* __restrict__ u, short* __restrict__ upk) {
    __shared__ short st[64 * 132];
    int tid = threadIdx.x, bid = blockIdx.x;   // 512 blocks: 64 m x 128 k each
    const float* up = u + (size_t)bid * 8192;
#pragma unroll
    for (int q = 0; q < 8; ++q) {
        int idx = q * 1024 + tid * 4;
        float4 v = *reinterpret_cast<const float4*>(up + idx);
        int m = idx >> 7, k = idx & 127;
        s16x4 pv;
        __hip_bfloat16 b0 = __float2bfloat16(v.x); pv[0] = *(short*)&b0;
        __hip_bfloat16 b1 = __float2bfloat16(v.y); pv[1] = *(short*)&b1;
        __hip_bfloat16 b2 = __float2bfloat16(v.z); pv[2] = *(short*)&b2;
        __hip_bfloat16 b3 = __float2bfloat16(v.w); pv[3] = *(short*)&b3;
        *reinterpret_cast<__shared__ s16x4*>(&st[m * 132 + k]) = pv;
    }
    __syncthreads();
    short* op = upk + (size_t)bid * 8192;
#pragma unroll
    for (int q2 = 0; q2 < 4; ++q2) {
        int o = q2 * 2048 + tid * 8;
        int ml = o & 15, k = (o >> 4) & 127, sl = o >> 11;
        s16x8 w;
#pragma unroll
        for (int r = 0; r < 8; ++r) w[r] = st[(sl * 16 + ml + r) * 132 + k];
        *reinterpret_cast<s16x8*>(op + o) = w;
    }
}

// ---- bf16 MFMA GEMM, 2-phase pipelined, 128x128 tile, 4 waves.
// Apk/Bpk packed: elem(row,k) at [(row>>4)*K + k]*16 + (row&15).
// PACKOUT=false: write f32 C[M][512], with xi0 fold for t==0 rows.
// PACKOUT=true: write packed bf16 (forcing).
template <int K, bool PACKOUT>
__global__ __launch_bounds__(256, 2) void gemm_mfma(const short* __restrict__ Apk,
                                                    const short* __restrict__ Bpk,
                                                    float* __restrict__ Cf,
                                                    short* __restrict__ Cp,
                                                    const float* __restrict__ xi0) {
    __shared__ __align__(1024) short lds[16384];   // A: [buf]*4096, B: 8192+[buf]*4096
    const int tid = threadIdx.x;
    const int wid = tid >> 6, lane = tid & 63;
    const int m0 = blockIdx.x * 128, n0 = blockIdx.y * 128;
    const int wm = wid >> 1, wn = wid & 1;
    f32x4 acc[4][4] = {};
    const size_t slabStride = (size_t)K * 16;
    const unsigned ldsBase = (unsigned)(uintptr_t)(__attribute__((address_space(3))) short*)&lds[0];

#define STAGE(buf, kk)                                                                              \
    do {                                                                                            \
        const short* gA0 = Apk + ((size_t)(m0 >> 4) + wid)     * slabStride + (size_t)(kk) * 16 + lane * 8; \
        const short* gA1 = Apk + ((size_t)(m0 >> 4) + wid + 4) * slabStride + (size_t)(kk) * 16 + lane * 8; \
        const short* gB0 = Bpk + ((size_t)(n0 >> 4) + wid)     * slabStride + (size_t)(kk) * 16 + lane * 8; \
        const short* gB1 = Bpk + ((size_t)(n0 >> 4) + wid + 4) * slabStride + (size_t)(kk) * 16 + lane * 8; \
        __builtin_amdgcn_global_load_lds((const __attribute__((address_space(1))) void*)gA0,        \
            (__attribute__((address_space(3))) void*)&lds[(buf) * 4096 + wid * 512], 16, 0, 0);     \
        __builtin_amdgcn_global_load_lds((const __attribute__((address_space(1))) void*)gA1,        \
            (__attribute__((address_space(3))) void*)&lds[(buf) * 4096 + (wid + 4) * 512], 16, 0, 0); \
        __builtin_amdgcn_global_load_lds((const __attribute__((address_space(1))) void*)gB0,        \
            (__attribute__((address_space(3))) void*)&lds[8192 + (buf) * 4096 + wid * 512], 16, 0, 0); \
        __builtin_amdgcn_global_load_lds((const __attribute__((address_space(1))) void*)gB1,        \
            (__attribute__((address_space(3))) void*)&lds[8192 + (buf) * 4096 + (wid + 4) * 512], 16, 0, 0); \
    } while (0)

    STAGE(0, 0);
    asm volatile("s_waitcnt vmcnt(0)" ::: "memory");
    __syncthreads();
    int cur = 0;
    for (int kk = 0; kk < K; kk += 32) {
        if (kk + 32 < K) STAGE(cur ^ 1, kk + 32);   // prefetch next tile under current compute

        s16x4 al[4], ah[4], bl[4], bh[4];
        const unsigned aB = ldsBase + (unsigned)cur * 8192;
        const unsigned bB = ldsBase + 16384u + (unsigned)cur * 8192;
#pragma unroll
        for (int t = 0; t < 4; ++t) {
            unsigned ad = aB + ((unsigned)(wm * 4 + t) << 10) + ((unsigned)lane << 3);
            unsigned bd = bB + ((unsigned)(wn * 4 + t) << 10) + ((unsigned)lane << 3);
            asm volatile("ds_read_b64_tr_b16 %0, %1 offset:0"   : "=v"(al[t]) : "v"(ad));
            asm volatile("ds_read_b64_tr_b16 %0, %1 offset:512" : "=v"(ah[t]) : "v"(ad));
            asm volatile("ds_read_b64_tr_b16 %0, %1 offset:0"   : "=v"(bl[t]) : "v"(bd));
            asm volatile("ds_read_b64_tr_b16 %0, %1 offset:512" : "=v"(bh[t]) : "v"(bd));
        }
        asm volatile("s_waitcnt lgkmcnt(0)" ::: "memory");
        __builtin_amdgcn_sched_barrier(0);   // rule 18

#pragma unroll
        for (int i = 0; i < 4; ++i) {
            s16x8 av = __builtin_shufflevector(al[i], ah[i], 0, 1, 2, 3, 4, 5, 6, 7);
#pragma unroll
            for (int j = 0; j < 4; ++j) {
                s16x8 bv = __builtin_shufflevector(bl[j], bh[j], 0, 1, 2, 3, 4, 5, 6, 7);
                acc[i][j] = __builtin_amdgcn_mfma_f32_16x16x32_bf16(av, bv, acc[i][j], 0, 0, 0);
            }
        }
        asm volatile("s_waitcnt vmcnt(0)" ::: "memory");   // next tile's loads landed
        __syncthreads();
        cur ^= 1;
    }
#undef STAGE

    const int cn = lane & 15;
    const int g4 = (lane >> 4) * 4;
    if (!PACKOUT) {
        // C/D layout: col = lane&15, row = (lane>>4)*4 + reg  [m89]
#pragma unroll
        for (int i = 0; i < 4; ++i) {
            int mrow = m0 + (wm * 4 + i) * 16 + g4;
#pragma unroll
            for (int j = 0; j < 4; ++j) {
                int ncol = n0 + (wn * 4 + j) * 16 + cn;
                float* cp = Cf + (size_t)mrow * TWO_N + ncol;
#pragma unroll
                for (int r = 0; r < 4; ++r) {
                    float v = acc[i][j][r];
                    if (((mrow + r) & (TSTEPS - 1)) == 0)   // t==0 row: out = xi_init
                        v = xi0[((mrow + r) >> 11) * TWO_N + ncol];
                    cp[(size_t)r * TWO_N] = v;
                }
            }
        }
    } else {
        // build packed-bf16 tile image in LDS: [8 s][128 cwt][16 ml], 32 KB
#pragma unroll
        for (int i = 0; i < 4; ++i) {
            int s = wm * 4 + i;
#pragma unroll
            for (int j = 0; j < 4; ++j) {
                int cwt = wn * 64 + j * 16 + cn;
                s16x4 pv;
#pragma unroll
                for (int r = 0; r < 4; ++r) {
                    __hip_bfloat16 bb = __float2bfloat16(acc[i][j][r]);
                    pv[r] = *reinterpret_cast<short*>(&bb);
                }
                *reinterpret_cast<__shared__ s16x4*>(&lds[((s * 128 + cwt) << 4) + g4]) = pv;
            }
        }
        __syncthreads();
        size_t baseG = (size_t)(m0 >> 4) * ((size_t)TWO_N * 16) + (size_t)n0 * 16;
#pragma unroll
        for (int q = 0; q < 8; ++q) {
            *reinterpret_cast<s16x8*>(Cp + baseG + (size_t)q * (TWO_N * 16) + tid * 8) =
                *reinterpret_cast<const __shared__ s16x8*>(&lds[q * 2048 + tid * 8]);
        }
    }
}

// ---- vectorized chunked diagonal scan (packed layout: thread's data is contiguous) ----
__global__ __launch_bounds__(256) void scan_passA(const short* __restrict__ Fpk,
                                                  const float* __restrict__ dbuf,
                                                  float* __restrict__ e) {
    int b = blockIdx.x, c = blockIdx.y, i = threadIdx.x;   // i = complex state 0..255
    float dr = dbuf[i], di = dbuf[N_ST + i];
    float re = 0.f, im = 0.f;
    int slab0 = (b * TSTEPS + c * CHUNKL) >> 4;   // 4 slabs per chunk
#pragma unroll
    for (int g = 0; g < 4; ++g) {
        const short* base = Fpk + (size_t)(slab0 + g) * 8192 + i * 16;
        s16x8 r0 = *reinterpret_cast<const s16x8*>(base);
        s16x8 r1 = *reinterpret_cast<const s16x8*>(base + 8);
        s16x8 i0 = *reinterpret_cast<const s16x8*>(base + 4096);
        s16x8 i1 = *reinterpret_cast<const s16x8*>(base + 4096 + 8);
#pragma unroll
        for (int j = 0; j < 16; ++j) {
            float fr = bf2f(j < 8 ? r0[j & 7] : r1[j & 7]);
            float fi = bf2f(j < 8 ? i0[j & 7] : i1[j & 7]);
            float nre = fmaf(dr, re, fmaf(-di, im, fr));
            float nim = fmaf(dr, im, fmaf(di, re, fi));
            re = nre; im = nim;
        }
    }
    size_t o = ((size_t)(b * NCHUNK + c)) * TWO_N;
    e[o + i] = re;
    e[o + N_ST + i] = im;
}

__global__ void scan_passB(const float* __restrict__ e, const float* __restrict__ dbuf,
                           const float* __restrict__ xbar0, float* __restrict__ cinit) {
    int b = blockIdx.x, i = threadIdx.x;
    float dLr = dbuf[2 * N_ST + i], dLi = dbuf[3 * N_ST + i];
    float re = xbar0[b * TWO_N + i], im = xbar0[b * TWO_N + N_ST + i];
    for (int c = 0; c < NCHUNK; ++c) {
        size_t o = ((size_t)(b * NCHUNK + c)) * TWO_N;
        cinit[o + i] = re;
        cinit[o + N_ST + i] = im;
        float er = e[o + i], ei = e[o + N_ST + i];
        float nre = dLr * re - dLi * im + er;
        float nim = dLr * im + dLi * re + ei;
        re = nre; im = nim;
    }
}

__global__ __launch_bounds__(256) void scan_passC(const short* __restrict__ Fpk,
                                                  const float* __restrict__ dbuf,
                                                  const float* __restrict__ cinit,
                                                  short* __restrict__ Zpk) {
    int b = blockIdx.x, c = blockIdx.y, i = threadIdx.x;
    float dr = dbuf[i], di = dbuf[N_ST + i];
    size_t o = ((size_t)(b * NCHUNK + c)) * TWO_N;
    float re = cinit[o + i], im = cinit[o + N_ST + i];
    int slab0 = (b * TSTEPS + c * CHUNKL) >> 4;
#pragma unroll
    for (int g = 0; g < 4; ++g) {
        const short* base = Fpk + (size_t)(slab0 + g) * 8192 + i * 16;
        s16x8 r0 = *reinterpret_cast<const s16x8*>(base);
        s16x8 r1 = *reinterpret_cast<const s16x8*>(base + 8);
        s16x8 i0 = *reinterpret_cast<const s16x8*>(base + 4096);
        s16x8 i1 = *reinterpret_cast<const s16x8*>(base + 4096 + 8);
        s16x8 zr0, zr1, zi0, zi1;
#pragma unroll
        for (int j = 0; j < 16; ++j) {
            float fr = bf2f(j < 8 ? r0[j & 7] : r1[j & 7]);
            float fi = bf2f(j < 8 ? i0[j & 7] : i1[j & 7]);
            float nre = fmaf(dr, re, fmaf(-di, im, fr));
            float nim = fmaf(dr, im, fmaf(di, re, fi));
            re = nre; im = nim;
            __hip_bfloat16 br = __float2bfloat16(re), bi = __float2bfloat16(im);
            if (j < 8) { zr0[j & 7] = *(short*)&br; zi0[j & 7] = *(short*)&bi; }
            else       { zr1[j & 7] = *(short*)&br; zi1[j & 7] = *(short*)&bi; }
        }
        short* zb = Zpk + (size_t)(slab0 + g) * 8192 + i * 16;
        *reinterpret_cast<s16x8*>(zb)            = zr0;
        *reinterpret_cast<s16x8*>(zb + 8)        = zr1;
        *reinterpret_cast<s16x8*>(zb + 4096)     = zi0;
        *reinterpret_cast<s16x8*>(zb + 4096 + 8) = zi1;
    }
}

extern "C" void kernel_launch(void* const* d_in, const int* in_sizes, int n_in,
                              void* d_out, int out_size, void* d_ws, size_t ws_size,
                              hipStream_t stream) {
    const float* xi_init = (const float*)d_in[0];
    const float* u_log   = (const float*)d_in[1];
    const float* alpha   = (const float*)d_in[2];
    const float* theta   = (const float*)d_in[3];
    const float* B_re    = (const float*)d_in[4];
    const float* B_im    = (const float*)d_in[5];
    const float* P_re    = (const float*)d_in[6];
    const float* P_im    = (const float*)d_in[7];
    const float* Pinv_re = (const float*)d_in[8];
    const float* Pinv_im = (const float*)d_in[9];
    float* out = (float*)d_out;
    float* ws  = (float*)d_ws;

    short* Fpk  = (short*)(ws + OFF_FPK);
    short* Zpk  = (short*)(ws + OFF_ZPK);
    short* upk  = (short*)(ws + OFF_UPK);
    short* Wtpk = (short*)(ws + OFF_WT);
    short* Wfpk = (short*)(ws + OFF_WF);
    float* dbuf  = ws + OFF_D;
    float* xbar0 = ws + OFF_XBAR0;
    float* e     = ws + OFF_E;
    float* cinit = ws + OFF_CINIT;

    prep_all<<<1281, 256, 0, stream>>>(P_re, P_im, B_re, B_im, alpha, theta,
                                       Wtpk, Wfpk, dbuf);
    xbar0_kernel<<<64, 256, 0, stream>>>(Pinv_re, Pinv_im, xi_init, xbar0);
    upack<<<MTOT / 64, 256, 0, stream>>>(u_log, upk);

    // forcing (packed bf16 out): F = h * u @ Bc^T
    gemm_mfma<NU, true><<<dim3(MTOT / 128, 4), 256, 0, stream>>>(
        upk, Wfpk, nullptr, Fpk, nullptr);

    // chunked diagonal scan (32 chunks of 64 steps)
    scan_passA<<<dim3(BATCH, NCHUNK), 256, 0, stream>>>(Fpk, dbuf, e);
    scan_passB<<<BATCH, 256, 0, stream>>>(e, dbuf, xbar0, cinit);
    scan_passC<<<dim3(BATCH, NCHUNK), 256, 0, stream>>>(Fpk, dbuf, cinit, Zpk);

    // output projection: out = Z @ W^T (f32 out, t==0 rows = xi_init folded in epilogue)
    gemm_mfma<TWO_N, false><<<dim3(MTOT / 128, 4), 256, 0, stream>>>(
        Zpk, Wtpk, out, nullptr, xi_init);
}